// Round 7
// baseline (1201.764 us; speedup 1.0000x reference)
//
#include <hip/hip_runtime.h>
#include <hip/hip_bf16.h>
#include <stdint.h>

#define M_TOK 8192
#define KDIM  4096
#define NDIM  11008
#define NBLK  256      // KDIM / 16
#define K2    8192     // KDIM * 2 bytes (row stride of xt/wd)

#define DQ_BLOCKS 11008   // (NDIM*KDIM)/16 elems per thread /256 threads
#define ROT_BLOCKS 8192   // 256 b * 32 m-chunks

typedef __bf16 bf16x8 __attribute__((ext_vector_type(8)));
typedef float  f32x4  __attribute__((ext_vector_type(4)));
typedef unsigned short ushort8 __attribute__((ext_vector_type(8)));
typedef int    int4v  __attribute__((ext_vector_type(4)));

__device__ __forceinline__ unsigned short f2b(float f) {
    union { float f; unsigned int i; } v; v.f = f;
    unsigned int u = v.i;
    unsigned int r = (u + 0x7fffu + ((u >> 16) & 1u)) >> 16;
    return (unsigned short)r;
}

__device__ __forceinline__ void gl_lds16(const void* g, void* l) {
    __builtin_amdgcn_global_load_lds(
        (const __attribute__((address_space(1))) unsigned int*)g,
        (__attribute__((address_space(3))) unsigned int*)l, 16, 0, 0);
}

// ---------------------------------------------------------------------------
// Fused prep. NT loads on one-shot inputs (x, qweight) so they don't evict
// the xt/wd working set from the MALL; xt/wd writes allocate normally.
// ---------------------------------------------------------------------------
__global__ __launch_bounds__(256) void prep_kernel(
    const float* __restrict__ x, const float* __restrict__ R,
    const int* __restrict__ perm, const int* __restrict__ qw,
    const float* __restrict__ scales, const float* __restrict__ zeros,
    unsigned short* __restrict__ xt, unsigned short* __restrict__ wd)
{
    const int bid = blockIdx.x;
    const int t   = threadIdx.x;

    if (bid < DQ_BLOCKS) {
        // ---- dequant: wd[n,k] = (q - zeros[n]) * scales[n] -> bf16 ----
        const size_t base = ((size_t)bid * 256 + t) * 16;
        const int n = (int)(base >> 12);        // /KDIM
        const float s = scales[n];
        const float z = zeros[n];
        const int4v* qp = (const int4v*)(qw + base);
        unsigned short o[16] __attribute__((aligned(16)));
#pragma unroll
        for (int c = 0; c < 4; ++c) {
            const int4v q4 = __builtin_nontemporal_load(qp + c);
            o[c*4+0] = f2b(((float)q4.x - z) * s);
            o[c*4+1] = f2b(((float)q4.y - z) * s);
            o[c*4+2] = f2b(((float)q4.z - z) * s);
            o[c*4+3] = f2b(((float)q4.w - z) * s);
        }
        *(ushort8*)(wd + base)     = *(ushort8*)o;
        *(ushort8*)(wd + base + 8) = *(ushort8*)(o + 8);
    } else {
        // ---- rotate: xt[m, b*16+j] = sum_i x[m, perm[b*16+i]] * R[b,i,j] ----
        __shared__ float Rs[16][17];
        __shared__ int   ps[16];
        const int rb = bid - DQ_BLOCKS;
        const int b  = rb & 255;
        const int mc = rb >> 8;
        Rs[t >> 4][t & 15] = R[b * 256 + t];
        if (t < 16) ps[t] = perm[b * 16 + t];
        __syncthreads();

        const int m = mc * 256 + t;
        const float* xrow = x + (size_t)m * KDIM;
        float xv[16];
#pragma unroll
        for (int i = 0; i < 16; ++i) xv[i] = __builtin_nontemporal_load(&xrow[ps[i]]);

        unsigned short o[16] __attribute__((aligned(16)));
#pragma unroll
        for (int j = 0; j < 16; ++j) {
            float acc = 0.f;
#pragma unroll
            for (int i = 0; i < 16; ++i) acc += xv[i] * Rs[i][j];
            o[j] = f2b(acc);
        }
        unsigned short* dst = xt + (size_t)m * KDIM + b * 16;
        *(ushort8*)dst       = *(ushort8*)o;
        *(ushort8*)(dst + 8) = *(ushort8*)(o + 8);
    }
}

// ---------------------------------------------------------------------------
// 256x256 8-phase GEMM (round-4 verified config): C[m,n] = sum_k A[m,k]*B[n,k]
// A: xt (M x K bf16), B: wd (N x K bf16), C: f32 via NONTEMPORAL stores
// (C is never re-read; keep it out of the MALL so A/B panels stay resident).
// 512 threads = 8 waves (2M x 4N); BK=64; LDS 128 KiB (2 buffers).
// mfma_f32_16x16x32_bf16; (row&7)<<4 XOR swizzle (0 conflicts measured);
// staging pre-swizzles the GLOBAL source, LDS dest linear; counted vmcnt(4).
// ---------------------------------------------------------------------------
#define ABASE(bb) ((bb)*65536)
#define BBASE(bb) ((bb)*65536 + 32768)

#define BAR() do { asm volatile("" ::: "memory"); __builtin_amdgcn_s_barrier(); \
                   asm volatile("" ::: "memory"); } while (0)
#define WAITV(n) asm volatile("s_waitcnt vmcnt(" #n ")" ::: "memory")
#define PRIO1 __builtin_amdgcn_s_setprio(1)
#define PRIO0 __builtin_amdgcn_s_setprio(0)

#define STAGE_A(bb, kB) do { \
    gl_lds16(aStageBase + (size_t)(  0)*K2 + (kB), lds + ABASE(bb) +     0 + wOff); \
    gl_lds16(aStageBase + (size_t)( 64)*K2 + (kB), lds + ABASE(bb) +  8192 + wOff); \
    gl_lds16(aStageBase + (size_t)(128)*K2 + (kB), lds + ABASE(bb) + 16384 + wOff); \
    gl_lds16(aStageBase + (size_t)(192)*K2 + (kB), lds + ABASE(bb) + 24576 + wOff); \
} while (0)
#define STAGE_B0(bb, kB) do { \
    gl_lds16(bStageBase + (size_t)(  0)*K2 + (kB), lds + BBASE(bb) +     0 + wOff); \
    gl_lds16(bStageBase + (size_t)( 64)*K2 + (kB), lds + BBASE(bb) +  8192 + wOff); \
} while (0)
#define STAGE_B1(bb, kB) do { \
    gl_lds16(bStageBase + (size_t)(128)*K2 + (kB), lds + BBASE(bb) + 16384 + wOff); \
    gl_lds16(bStageBase + (size_t)(192)*K2 + (kB), lds + BBASE(bb) + 24576 + wOff); \
} while (0)

#define PH_READ_A(bb, mh) do { \
    _Pragma("unroll") \
    for (int mf = 0; mf < 4; ++mf) { \
        aF[mf][0] = *(const bf16x8*)(lds + ABASE(bb) + aRdBase + ((mh)*64 + mf*16)*128 + cs0); \
        aF[mf][1] = *(const bf16x8*)(lds + ABASE(bb) + aRdBase + ((mh)*64 + mf*16)*128 + cs1); \
    } \
} while (0)
#define PH_READ_B(bb, nh) do { \
    _Pragma("unroll") \
    for (int nf = 0; nf < 2; ++nf) { \
        bF[nh][nf][0] = *(const bf16x8*)(lds + BBASE(bb) + bRdBase + ((nh)*32 + nf*16)*128 + cs0); \
        bF[nh][nf][1] = *(const bf16x8*)(lds + BBASE(bb) + bRdBase + ((nh)*32 + nf*16)*128 + cs1); \
    } \
} while (0)

#define MFMA_Q(mh, nh) do { \
    _Pragma("unroll") \
    for (int mf = 0; mf < 4; ++mf) \
    _Pragma("unroll") \
    for (int nf = 0; nf < 2; ++nf) { \
        acc[(mh)*4+mf][(nh)*2+nf] = __builtin_amdgcn_mfma_f32_16x16x32_bf16( \
            aF[mf][0], bF[nh][nf][0], acc[(mh)*4+mf][(nh)*2+nf], 0, 0, 0); \
        acc[(mh)*4+mf][(nh)*2+nf] = __builtin_amdgcn_mfma_f32_16x16x32_bf16( \
            aF[mf][1], bF[nh][nf][1], acc[(mh)*4+mf][(nh)*2+nf], 0, 0, 0); \
    } \
} while (0)

// MODE: 0 steady, 1 tail (stage B of t+1 only, drain), 2 last (compute only)
#define TILE(bb, kB, MODE) do { \
    PH_READ_A(bb, 0); PH_READ_B(bb, 0); \
    if ((MODE) <= 1) STAGE_B0((bb)^1, (kB) + 128); \
    BAR(); PRIO1; MFMA_Q(0, 0); PRIO0; BAR(); \
    PH_READ_B(bb, 1); \
    if ((MODE) <= 1) STAGE_B1((bb)^1, (kB) + 128); \
    BAR(); PRIO1; MFMA_Q(0, 1); PRIO0; BAR(); \
    PH_READ_A(bb, 1); \
    BAR(); PRIO1; MFMA_Q(1, 0); PRIO0; BAR(); \
    if ((MODE) == 0) STAGE_A(bb, (kB) + 256); \
    PRIO1; MFMA_Q(1, 1); PRIO0; \
    if ((MODE) == 0) WAITV(4); \
    if ((MODE) == 1) WAITV(0); \
    BAR(); \
} while (0)

__global__ __launch_bounds__(512, 2) void gemm_bt256(
    const unsigned short* __restrict__ Aq, const unsigned short* __restrict__ Bq,
    float* __restrict__ C)
{
    __shared__ char lds[131072];

    const int tid  = threadIdx.x;
    const int wave = tid >> 6;
    const int lane = tid & 63;
    const int wr   = wave >> 2;      // 0..1 (M)
    const int wc   = wave & 3;       // 0..3 (N)

    // XCD-aware bijective swizzle: 1376 wg = 8 * 172; tn-major (tm fastest)
    const int wg  = blockIdx.x;
    const int swz = (wg & 7) * 172 + (wg >> 3);
    const int tm  = swz & 31;        // M/256 = 32
    const int tn  = swz >> 5;        // N/256 = 43

    // ---- staging (pre-swizzled global source, linear LDS dest) ----
    const int gRow    = wave * 8 + (lane >> 3);
    const int gColSwz = (((lane & 7) ^ ((lane >> 3) & 7)) << 4);
    const char* aStageBase = (const char*)Aq + (size_t)(tm * 256 + gRow) * K2 + gColSwz;
    const char* bStageBase = (const char*)Bq + (size_t)(tn * 256 + gRow) * K2 + gColSwz;
    const int wOff = wave * 1024;

    // ---- ds_read addressing (swizzled) ----
    const int laneRow128 = (lane & 15) * 128;
    const int lx  = (lane & 7) << 4;
    const int cs0 = (((lane >> 4) * 16)      ) ^ lx;   // k-cols 0..31
    const int cs1 = (((lane >> 4) * 16) + 64 ) ^ lx;   // k-cols 32..63
    const int aRdBase = wr * 16384 + laneRow128;
    const int bRdBase = (wc >> 1) * 16384 + (wc & 1) * 8192 + laneRow128;

    f32x4  acc[8][4] = {};
    bf16x8 aF[4][2];
    bf16x8 bF[2][2][2];

    // ---- prologue: tile0 (A,B) + tile1 (A) ----
    STAGE_A(0, 0);
    STAGE_B0(0, 0); STAGE_B1(0, 0);
    STAGE_A(1, 128);
    WAITV(4);
    BAR();

    int kB = 0;
#pragma unroll 1
    for (int t = 0; t < 61; t += 2) {
        TILE(0, kB, 0);
        TILE(1, kB + 128, 0);
        kB += 256;
    }
    TILE(0, 62 * 128, 1);
    TILE(1, 63 * 128, 2);

    // ---- epilogue: C/D layout col = lane&15, row = (lane>>4)*4 + reg ----
    // NONTEMPORAL stores: C is write-once, never re-read by this kernel.
    const int row0 = tm * 256 + wr * 128 + (lane >> 4) * 4;
    const int col0 = tn * 256 + wc * 64 + (lane & 15);
#pragma unroll
    for (int mi = 0; mi < 8; ++mi) {
#pragma unroll
        for (int ni = 0; ni < 4; ++ni) {
            const f32x4 v = acc[mi][ni];
            const size_t r = (size_t)(row0 + mi * 16);
            const int    c = col0 + ni * 16;
            __builtin_nontemporal_store(v[0], &C[(r + 0) * NDIM + c]);
            __builtin_nontemporal_store(v[1], &C[(r + 1) * NDIM + c]);
            __builtin_nontemporal_store(v[2], &C[(r + 2) * NDIM + c]);
            __builtin_nontemporal_store(v[3], &C[(r + 3) * NDIM + c]);
        }
    }
}

extern "C" void kernel_launch(void* const* d_in, const int* in_sizes, int n_in,
                              void* d_out, int out_size, void* d_ws, size_t ws_size,
                              hipStream_t stream) {
    const float* x      = (const float*)d_in[0];
    const float* R      = (const float*)d_in[1];
    const float* scales = (const float*)d_in[2];
    const float* zeros  = (const float*)d_in[3];
    const int*   perm   = (const int*)d_in[4];
    const int*   qw     = (const int*)d_in[5];
    float*       out    = (float*)d_out;

    unsigned short* xt = (unsigned short*)d_ws;          // 64 MiB
    unsigned short* wd = xt + (size_t)M_TOK * KDIM;      // 86 MiB

    prep_kernel<<<dim3(DQ_BLOCKS + ROT_BLOCKS), 256, 0, stream>>>(
        x, R, perm, qw, scales, zeros, xt, wd);
    gemm_bt256<<<dim3((M_TOK / 256) * (NDIM / 256)), 512, 0, stream>>>(xt, wd, out);
}

// Round 8
// 793.954 us; speedup vs baseline: 1.5136x; 1.5136x over previous
//
#include <hip/hip_runtime.h>
#include <hip/hip_bf16.h>
#include <stdint.h>

#define M_TOK 8192
#define KDIM  4096
#define NDIM  11008
#define K2    8192     // KDIM * 2 bytes (row stride of xt/wd)

typedef __bf16 bf16x8 __attribute__((ext_vector_type(8)));
typedef float  f32x4  __attribute__((ext_vector_type(4)));
typedef unsigned short ushort8 __attribute__((ext_vector_type(8)));

__device__ __forceinline__ unsigned short f2b(float f) {
    union { float f; unsigned int i; } v; v.f = f;
    unsigned int u = v.i;
    unsigned int r = (u + 0x7fffu + ((u >> 16) & 1u)) >> 16;
    return (unsigned short)r;
}

__device__ __forceinline__ void gl_lds16(const void* g, void* l) {
    __builtin_amdgcn_global_load_lds(
        (const __attribute__((address_space(1))) unsigned int*)g,
        (__attribute__((address_space(3))) unsigned int*)l, 16, 0, 0);
}

// ---------------------------------------------------------------------------
// Rotate (write-coalesced): block = 16 rows x 16 b-blocks (256 cols of K).
// Thread (r, bs) computes xt[m0+r, bg*256 + bs*16 .. +16] -> one 32-B run;
// per store instruction the wave emits 4 x 256-B contiguous runs (full lines),
// vs the old layout's 64 x 16-B scattered segments (4x write inflation).
// grid: (KDIM/256 = 16, M_TOK/16 = 512), block 256.
// ---------------------------------------------------------------------------
__global__ __launch_bounds__(256) void rotate_kernel(
    const float* __restrict__ x, const float* __restrict__ R,
    const int* __restrict__ perm, unsigned short* __restrict__ xt)
{
    __shared__ float Rs[16 * 273];   // [bs]*273 + [i]*17 + [j]: 16 banks + bcast
    __shared__ int   ps[256];
    const int bg = blockIdx.x;       // K-group of 16 b-blocks
    const int mc = blockIdx.y;       // row chunk of 16
    const int t  = threadIdx.x;

    ps[t] = perm[bg * 256 + t];
    {
        const float* Rg = R + (size_t)bg * 4096;
#pragma unroll
        for (int k = 0; k < 16; ++k) {
            const int idx = t * 16 + k;       // coalesced 64B/thread source
            const int bs = idx >> 8;
            const int i  = (idx >> 4) & 15;
            const int j  = idx & 15;
            Rs[bs * 273 + i * 17 + j] = Rg[idx];
        }
    }
    __syncthreads();

    const int bs = t & 15;
    const int r  = t >> 4;
    const int m  = mc * 16 + r;
    const float* xrow = x + (size_t)m * KDIM;

    float xv[16];
#pragma unroll
    for (int i = 0; i < 16; ++i) xv[i] = xrow[ps[bs * 16 + i]];

    float o[16];
#pragma unroll
    for (int j = 0; j < 16; ++j) o[j] = 0.f;
#pragma unroll
    for (int i = 0; i < 16; ++i) {
        const float xi = xv[i];
        const float* Rrow = &Rs[bs * 273 + i * 17];
#pragma unroll
        for (int j = 0; j < 16; ++j) o[j] += xi * Rrow[j];
    }

    unsigned short os[16] __attribute__((aligned(16)));
#pragma unroll
    for (int j = 0; j < 16; ++j) os[j] = f2b(o[j]);
    unsigned short* dst = xt + (size_t)m * KDIM + bg * 256 + bs * 16;
    *(ushort8*)dst       = *(ushort8*)os;
    *(ushort8*)(dst + 8) = *(ushort8*)(os + 8);
}

// ---------------------------------------------------------------------------
// Dequant: wd[n,k] = (float(q[n,k]) - zeros[n]) * scales[n] -> bf16
// ---------------------------------------------------------------------------
__global__ __launch_bounds__(256) void dequant_kernel(
    const int* __restrict__ q, const float* __restrict__ scales,
    const float* __restrict__ zeros, unsigned short* __restrict__ w)
{
    const int idx8 = blockIdx.x * 256 + threadIdx.x;
    const size_t base = (size_t)idx8 * 8;
    const int n = (int)(base >> 12);
    const float s = scales[n];
    const float z = zeros[n];
    const int4* qp = (const int4*)(q + base);
    const int4 q0 = qp[0], q1 = qp[1];
    unsigned short o[8] __attribute__((aligned(16)));
    o[0] = f2b(((float)q0.x - z) * s);
    o[1] = f2b(((float)q0.y - z) * s);
    o[2] = f2b(((float)q0.z - z) * s);
    o[3] = f2b(((float)q0.w - z) * s);
    o[4] = f2b(((float)q1.x - z) * s);
    o[5] = f2b(((float)q1.y - z) * s);
    o[6] = f2b(((float)q1.z - z) * s);
    o[7] = f2b(((float)q1.w - z) * s);
    *(ushort8*)(w + base) = *(ushort8*)o;
}

// ---------------------------------------------------------------------------
// 256x256 8-phase GEMM (round-4 verified config, NT reverted):
// C[m,n] = sum_k A[m,k]*B[n,k]; A: xt, B: wd (bf16); C f32.
// 512 threads = 8 waves (2M x 4N); BK=64; LDS 128 KiB (2 buffers).
// mfma_f32_16x16x32_bf16; (row&7)<<4 XOR swizzle (0 conflicts measured);
// staging pre-swizzles the GLOBAL source, LDS dest linear; counted vmcnt(4).
// ---------------------------------------------------------------------------
#define ABASE(bb) ((bb)*65536)
#define BBASE(bb) ((bb)*65536 + 32768)

#define BAR() do { asm volatile("" ::: "memory"); __builtin_amdgcn_s_barrier(); \
                   asm volatile("" ::: "memory"); } while (0)
#define WAITV(n) asm volatile("s_waitcnt vmcnt(" #n ")" ::: "memory")
#define PRIO1 __builtin_amdgcn_s_setprio(1)
#define PRIO0 __builtin_amdgcn_s_setprio(0)

#define STAGE_A(bb, kB) do { \
    gl_lds16(aStageBase + (size_t)(  0)*K2 + (kB), lds + ABASE(bb) +     0 + wOff); \
    gl_lds16(aStageBase + (size_t)( 64)*K2 + (kB), lds + ABASE(bb) +  8192 + wOff); \
    gl_lds16(aStageBase + (size_t)(128)*K2 + (kB), lds + ABASE(bb) + 16384 + wOff); \
    gl_lds16(aStageBase + (size_t)(192)*K2 + (kB), lds + ABASE(bb) + 24576 + wOff); \
} while (0)
#define STAGE_B0(bb, kB) do { \
    gl_lds16(bStageBase + (size_t)(  0)*K2 + (kB), lds + BBASE(bb) +     0 + wOff); \
    gl_lds16(bStageBase + (size_t)( 64)*K2 + (kB), lds + BBASE(bb) +  8192 + wOff); \
} while (0)
#define STAGE_B1(bb, kB) do { \
    gl_lds16(bStageBase + (size_t)(128)*K2 + (kB), lds + BBASE(bb) + 16384 + wOff); \
    gl_lds16(bStageBase + (size_t)(192)*K2 + (kB), lds + BBASE(bb) + 24576 + wOff); \
} while (0)

#define PH_READ_A(bb, mh) do { \
    _Pragma("unroll") \
    for (int mf = 0; mf < 4; ++mf) { \
        aF[mf][0] = *(const bf16x8*)(lds + ABASE(bb) + aRdBase + ((mh)*64 + mf*16)*128 + cs0); \
        aF[mf][1] = *(const bf16x8*)(lds + ABASE(bb) + aRdBase + ((mh)*64 + mf*16)*128 + cs1); \
    } \
} while (0)
#define PH_READ_B(bb, nh) do { \
    _Pragma("unroll") \
    for (int nf = 0; nf < 2; ++nf) { \
        bF[nh][nf][0] = *(const bf16x8*)(lds + BBASE(bb) + bRdBase + ((nh)*32 + nf*16)*128 + cs0); \
        bF[nh][nf][1] = *(const bf16x8*)(lds + BBASE(bb) + bRdBase + ((nh)*32 + nf*16)*128 + cs1); \
    } \
} while (0)

#define MFMA_Q(mh, nh) do { \
    _Pragma("unroll") \
    for (int mf = 0; mf < 4; ++mf) \
    _Pragma("unroll") \
    for (int nf = 0; nf < 2; ++nf) { \
        acc[(mh)*4+mf][(nh)*2+nf] = __builtin_amdgcn_mfma_f32_16x16x32_bf16( \
            aF[mf][0], bF[nh][nf][0], acc[(mh)*4+mf][(nh)*2+nf], 0, 0, 0); \
        acc[(mh)*4+mf][(nh)*2+nf] = __builtin_amdgcn_mfma_f32_16x16x32_bf16( \
            aF[mf][1], bF[nh][nf][1], acc[(mh)*4+mf][(nh)*2+nf], 0, 0, 0); \
    } \
} while (0)

// MODE: 0 steady, 1 tail (stage B of t+1 only, drain), 2 last (compute only)
#define TILE(bb, kB, MODE) do { \
    PH_READ_A(bb, 0); PH_READ_B(bb, 0); \
    if ((MODE) <= 1) STAGE_B0((bb)^1, (kB) + 128); \
    BAR(); PRIO1; MFMA_Q(0, 0); PRIO0; BAR(); \
    PH_READ_B(bb, 1); \
    if ((MODE) <= 1) STAGE_B1((bb)^1, (kB) + 128); \
    BAR(); PRIO1; MFMA_Q(0, 1); PRIO0; BAR(); \
    PH_READ_A(bb, 1); \
    BAR(); PRIO1; MFMA_Q(1, 0); PRIO0; BAR(); \
    if ((MODE) == 0) STAGE_A(bb, (kB) + 256); \
    PRIO1; MFMA_Q(1, 1); PRIO0; \
    if ((MODE) == 0) WAITV(4); \
    if ((MODE) == 1) WAITV(0); \
    BAR(); \
} while (0)

__global__ __launch_bounds__(512, 2) void gemm_bt256(
    const unsigned short* __restrict__ Aq, const unsigned short* __restrict__ Bq,
    float* __restrict__ C)
{
    __shared__ char lds[131072];

    const int tid  = threadIdx.x;
    const int wave = tid >> 6;
    const int lane = tid & 63;
    const int wr   = wave >> 2;      // 0..1 (M)
    const int wc   = wave & 3;       // 0..3 (N)

    // XCD-aware bijective swizzle: 1376 wg = 8 * 172; tn-major (tm fastest)
    const int wg  = blockIdx.x;
    const int swz = (wg & 7) * 172 + (wg >> 3);
    const int tm  = swz & 31;        // M/256 = 32
    const int tn  = swz >> 5;        // N/256 = 43

    // ---- staging (pre-swizzled global source, linear LDS dest) ----
    const int gRow    = wave * 8 + (lane >> 3);
    const int gColSwz = (((lane & 7) ^ ((lane >> 3) & 7)) << 4);
    const char* aStageBase = (const char*)Aq + (size_t)(tm * 256 + gRow) * K2 + gColSwz;
    const char* bStageBase = (const char*)Bq + (size_t)(tn * 256 + gRow) * K2 + gColSwz;
    const int wOff = wave * 1024;

    // ---- ds_read addressing (swizzled) ----
    const int laneRow128 = (lane & 15) * 128;
    const int lx  = (lane & 7) << 4;
    const int cs0 = (((lane >> 4) * 16)      ) ^ lx;   // k-cols 0..31
    const int cs1 = (((lane >> 4) * 16) + 64 ) ^ lx;   // k-cols 32..63
    const int aRdBase = wr * 16384 + laneRow128;
    const int bRdBase = (wc >> 1) * 16384 + (wc & 1) * 8192 + laneRow128;

    f32x4  acc[8][4] = {};
    bf16x8 aF[4][2];
    bf16x8 bF[2][2][2];

    // ---- prologue: tile0 (A,B) + tile1 (A) ----
    STAGE_A(0, 0);
    STAGE_B0(0, 0); STAGE_B1(0, 0);
    STAGE_A(1, 128);
    WAITV(4);
    BAR();

    int kB = 0;
#pragma unroll 1
    for (int t = 0; t < 61; t += 2) {
        TILE(0, kB, 0);
        TILE(1, kB + 128, 0);
        kB += 256;
    }
    TILE(0, 62 * 128, 1);
    TILE(1, 63 * 128, 2);

    // ---- epilogue: C/D layout col = lane&15, row = (lane>>4)*4 + reg ----
    const int row0 = tm * 256 + wr * 128 + (lane >> 4) * 4;
    const int col0 = tn * 256 + wc * 64 + (lane & 15);
#pragma unroll
    for (int mi = 0; mi < 8; ++mi) {
#pragma unroll
        for (int ni = 0; ni < 4; ++ni) {
            const f32x4 v = acc[mi][ni];
            const size_t r = (size_t)(row0 + mi * 16);
            const int    c = col0 + ni * 16;
            C[(r + 0) * NDIM + c] = v[0];
            C[(r + 1) * NDIM + c] = v[1];
            C[(r + 2) * NDIM + c] = v[2];
            C[(r + 3) * NDIM + c] = v[3];
        }
    }
}

extern "C" void kernel_launch(void* const* d_in, const int* in_sizes, int n_in,
                              void* d_out, int out_size, void* d_ws, size_t ws_size,
                              hipStream_t stream) {
    const float* x      = (const float*)d_in[0];
    const float* R      = (const float*)d_in[1];
    const float* scales = (const float*)d_in[2];
    const float* zeros  = (const float*)d_in[3];
    const int*   perm   = (const int*)d_in[4];
    const int*   qw     = (const int*)d_in[5];
    float*       out    = (float*)d_out;

    unsigned short* xt = (unsigned short*)d_ws;          // 64 MiB
    unsigned short* wd = xt + (size_t)M_TOK * KDIM;      // 86 MiB

    rotate_kernel<<<dim3(KDIM / 256, M_TOK / 16), 256, 0, stream>>>(x, R, perm, xt);
    dequant_kernel<<<dim3((int)(((size_t)NDIM * KDIM) / 8 / 256)), 256, 0, stream>>>(qw, scales, zeros, wd);
    gemm_bt256<<<dim3((M_TOK / 256) * (NDIM / 256)), 512, 0, stream>>>(xt, wd, out);
}

// Round 9
// 752.614 us; speedup vs baseline: 1.5968x; 1.0549x over previous
//
#include <hip/hip_runtime.h>
#include <hip/hip_bf16.h>
#include <stdint.h>

#define M_TOK 8192
#define KDIM  4096
#define NDIM  11008
#define K2    8192     // KDIM * 2 bytes (row stride of xt/wd)

typedef __bf16 bf16x8 __attribute__((ext_vector_type(8)));
typedef float  f32x4  __attribute__((ext_vector_type(4)));
typedef unsigned short ushort8 __attribute__((ext_vector_type(8)));

__device__ __forceinline__ unsigned short f2b(float f) {
    union { float f; unsigned int i; } v; v.f = f;
    unsigned int u = v.i;
    unsigned int r = (u + 0x7fffu + ((u >> 16) & 1u)) >> 16;
    return (unsigned short)r;
}

__device__ __forceinline__ void gl_lds16(const void* g, void* l) {
    __builtin_amdgcn_global_load_lds(
        (const __attribute__((address_space(1))) unsigned int*)g,
        (__attribute__((address_space(3))) unsigned int*)l, 16, 0, 0);
}

// ---------------------------------------------------------------------------
// Rotate (write-coalesced, round-8 verified): block = 16 rows x 16 b-blocks.
// ---------------------------------------------------------------------------
__global__ __launch_bounds__(256) void rotate_kernel(
    const float* __restrict__ x, const float* __restrict__ R,
    const int* __restrict__ perm, unsigned short* __restrict__ xt)
{
    __shared__ float Rs[16 * 273];   // [bs]*273 + [i]*17 + [j]
    __shared__ int   ps[256];
    const int bg = blockIdx.x;
    const int mc = blockIdx.y;
    const int t  = threadIdx.x;

    ps[t] = perm[bg * 256 + t];
    {
        const float* Rg = R + (size_t)bg * 4096;
#pragma unroll
        for (int k = 0; k < 16; ++k) {
            const int idx = t * 16 + k;
            const int bs = idx >> 8;
            const int i  = (idx >> 4) & 15;
            const int j  = idx & 15;
            Rs[bs * 273 + i * 17 + j] = Rg[idx];
        }
    }
    __syncthreads();

    const int bs = t & 15;
    const int r  = t >> 4;
    const int m  = mc * 16 + r;
    const float* xrow = x + (size_t)m * KDIM;

    float xv[16];
#pragma unroll
    for (int i = 0; i < 16; ++i) xv[i] = xrow[ps[bs * 16 + i]];

    float o[16];
#pragma unroll
    for (int j = 0; j < 16; ++j) o[j] = 0.f;
#pragma unroll
    for (int i = 0; i < 16; ++i) {
        const float xi = xv[i];
        const float* Rrow = &Rs[bs * 273 + i * 17];
#pragma unroll
        for (int j = 0; j < 16; ++j) o[j] += xi * Rrow[j];
    }

    unsigned short os[16] __attribute__((aligned(16)));
#pragma unroll
    for (int j = 0; j < 16; ++j) os[j] = f2b(o[j]);
    unsigned short* dst = xt + (size_t)m * KDIM + bg * 256 + bs * 16;
    *(ushort8*)dst       = *(ushort8*)os;
    *(ushort8*)(dst + 8) = *(ushort8*)(os + 8);
}

// ---------------------------------------------------------------------------
// Dequant: wd[n,k] = (float(q[n,k]) - zeros[n]) * scales[n] -> bf16
// ---------------------------------------------------------------------------
__global__ __launch_bounds__(256) void dequant_kernel(
    const int* __restrict__ q, const float* __restrict__ scales,
    const float* __restrict__ zeros, unsigned short* __restrict__ w)
{
    const int idx8 = blockIdx.x * 256 + threadIdx.x;
    const size_t base = (size_t)idx8 * 8;
    const int n = (int)(base >> 12);
    const float s = scales[n];
    const float z = zeros[n];
    const int4* qp = (const int4*)(q + base);
    const int4 q0 = qp[0], q1 = qp[1];
    unsigned short o[8] __attribute__((aligned(16)));
    o[0] = f2b(((float)q0.x - z) * s);
    o[1] = f2b(((float)q0.y - z) * s);
    o[2] = f2b(((float)q0.z - z) * s);
    o[3] = f2b(((float)q0.w - z) * s);
    o[4] = f2b(((float)q1.x - z) * s);
    o[5] = f2b(((float)q1.y - z) * s);
    o[6] = f2b(((float)q1.z - z) * s);
    o[7] = f2b(((float)q1.w - z) * s);
    *(ushort8*)(w + base) = *(ushort8*)o;
}

// ---------------------------------------------------------------------------
// 256x256 8-phase GEMM (round-4 verified schedule). ONLY change this round:
// 2D super-tiled dispatch order. Within each XCD chunk, canonical id runs in
// 4-tn-wide stripes ordered tm*4+tn_local, so ~32 consecutive ids (the
// resident window per XCD) form an 8tm x 4tn block: unique working set
// 24 MB/XCD (192 MB chip, L3-fits) vs 66 MB with column order -> less L3
// thrash, lower HBM fetch, faster stage returns.
// ---------------------------------------------------------------------------
#define ABASE(bb) ((bb)*65536)
#define BBASE(bb) ((bb)*65536 + 32768)

#define BAR() do { asm volatile("" ::: "memory"); __builtin_amdgcn_s_barrier(); \
                   asm volatile("" ::: "memory"); } while (0)
#define WAITV(n) asm volatile("s_waitcnt vmcnt(" #n ")" ::: "memory")
#define PRIO1 __builtin_amdgcn_s_setprio(1)
#define PRIO0 __builtin_amdgcn_s_setprio(0)

#define STAGE_A(bb, kB) do { \
    gl_lds16(aStageBase + (size_t)(  0)*K2 + (kB), lds + ABASE(bb) +     0 + wOff); \
    gl_lds16(aStageBase + (size_t)( 64)*K2 + (kB), lds + ABASE(bb) +  8192 + wOff); \
    gl_lds16(aStageBase + (size_t)(128)*K2 + (kB), lds + ABASE(bb) + 16384 + wOff); \
    gl_lds16(aStageBase + (size_t)(192)*K2 + (kB), lds + ABASE(bb) + 24576 + wOff); \
} while (0)
#define STAGE_B0(bb, kB) do { \
    gl_lds16(bStageBase + (size_t)(  0)*K2 + (kB), lds + BBASE(bb) +     0 + wOff); \
    gl_lds16(bStageBase + (size_t)( 64)*K2 + (kB), lds + BBASE(bb) +  8192 + wOff); \
} while (0)
#define STAGE_B1(bb, kB) do { \
    gl_lds16(bStageBase + (size_t)(128)*K2 + (kB), lds + BBASE(bb) + 16384 + wOff); \
    gl_lds16(bStageBase + (size_t)(192)*K2 + (kB), lds + BBASE(bb) + 24576 + wOff); \
} while (0)

#define PH_READ_A(bb, mh) do { \
    _Pragma("unroll") \
    for (int mf = 0; mf < 4; ++mf) { \
        aF[mf][0] = *(const bf16x8*)(lds + ABASE(bb) + aRdBase + ((mh)*64 + mf*16)*128 + cs0); \
        aF[mf][1] = *(const bf16x8*)(lds + ABASE(bb) + aRdBase + ((mh)*64 + mf*16)*128 + cs1); \
    } \
} while (0)
#define PH_READ_B(bb, nh) do { \
    _Pragma("unroll") \
    for (int nf = 0; nf < 2; ++nf) { \
        bF[nh][nf][0] = *(const bf16x8*)(lds + BBASE(bb) + bRdBase + ((nh)*32 + nf*16)*128 + cs0); \
        bF[nh][nf][1] = *(const bf16x8*)(lds + BBASE(bb) + bRdBase + ((nh)*32 + nf*16)*128 + cs1); \
    } \
} while (0)

#define MFMA_Q(mh, nh) do { \
    _Pragma("unroll") \
    for (int mf = 0; mf < 4; ++mf) \
    _Pragma("unroll") \
    for (int nf = 0; nf < 2; ++nf) { \
        acc[(mh)*4+mf][(nh)*2+nf] = __builtin_amdgcn_mfma_f32_16x16x32_bf16( \
            aF[mf][0], bF[nh][nf][0], acc[(mh)*4+mf][(nh)*2+nf], 0, 0, 0); \
        acc[(mh)*4+mf][(nh)*2+nf] = __builtin_amdgcn_mfma_f32_16x16x32_bf16( \
            aF[mf][1], bF[nh][nf][1], acc[(mh)*4+mf][(nh)*2+nf], 0, 0, 0); \
    } \
} while (0)

// MODE: 0 steady, 1 tail (stage B of t+1 only, drain), 2 last (compute only)
#define TILE(bb, kB, MODE) do { \
    PH_READ_A(bb, 0); PH_READ_B(bb, 0); \
    if ((MODE) <= 1) STAGE_B0((bb)^1, (kB) + 128); \
    BAR(); PRIO1; MFMA_Q(0, 0); PRIO0; BAR(); \
    PH_READ_B(bb, 1); \
    if ((MODE) <= 1) STAGE_B1((bb)^1, (kB) + 128); \
    BAR(); PRIO1; MFMA_Q(0, 1); PRIO0; BAR(); \
    PH_READ_A(bb, 1); \
    BAR(); PRIO1; MFMA_Q(1, 0); PRIO0; BAR(); \
    if ((MODE) == 0) STAGE_A(bb, (kB) + 256); \
    PRIO1; MFMA_Q(1, 1); PRIO0; \
    if ((MODE) == 0) WAITV(4); \
    if ((MODE) == 1) WAITV(0); \
    BAR(); \
} while (0)

__global__ __launch_bounds__(512, 2) void gemm_bt256(
    const unsigned short* __restrict__ Aq, const unsigned short* __restrict__ Bq,
    float* __restrict__ C)
{
    __shared__ char lds[131072];

    const int tid  = threadIdx.x;
    const int wave = tid >> 6;
    const int lane = tid & 63;
    const int wr   = wave >> 2;      // 0..1 (M)
    const int wc   = wave & 3;       // 0..3 (N)

    // XCD-aware chunking (1376 = 8 * 172), then 2D super-tiled canonical id:
    // stripes of 4 tn columns (last stripe 3), within-stripe order tm*4+tn.
    const int wg  = blockIdx.x;
    const int swz = (wg & 7) * 172 + (wg >> 3);
    int tm, tn;
    if (swz < 1280) {                 // stripes 0..9: tn 4S..4S+3
        const int S = swz >> 7;
        const int L = swz & 127;
        tm = L >> 2;
        tn = (S << 2) + (L & 3);
    } else {                          // stripe 10: tn 40..42 (3-wide)
        const int L = swz - 1280;     // 0..95
        tm = L / 3;
        tn = 40 + (L - tm * 3);
    }

    // ---- staging (pre-swizzled global source, linear LDS dest) ----
    const int gRow    = wave * 8 + (lane >> 3);
    const int gColSwz = (((lane & 7) ^ ((lane >> 3) & 7)) << 4);
    const char* aStageBase = (const char*)Aq + (size_t)(tm * 256 + gRow) * K2 + gColSwz;
    const char* bStageBase = (const char*)Bq + (size_t)(tn * 256 + gRow) * K2 + gColSwz;
    const int wOff = wave * 1024;

    // ---- ds_read addressing (swizzled) ----
    const int laneRow128 = (lane & 15) * 128;
    const int lx  = (lane & 7) << 4;
    const int cs0 = (((lane >> 4) * 16)      ) ^ lx;   // k-cols 0..31
    const int cs1 = (((lane >> 4) * 16) + 64 ) ^ lx;   // k-cols 32..63
    const int aRdBase = wr * 16384 + laneRow128;
    const int bRdBase = (wc >> 1) * 16384 + (wc & 1) * 8192 + laneRow128;

    f32x4  acc[8][4] = {};
    bf16x8 aF[4][2];
    bf16x8 bF[2][2][2];

    // ---- prologue: tile0 (A,B) + tile1 (A) ----
    STAGE_A(0, 0);
    STAGE_B0(0, 0); STAGE_B1(0, 0);
    STAGE_A(1, 128);
    WAITV(4);
    BAR();

    int kB = 0;
#pragma unroll 1
    for (int t = 0; t < 61; t += 2) {
        TILE(0, kB, 0);
        TILE(1, kB + 128, 0);
        kB += 256;
    }
    TILE(0, 62 * 128, 1);
    TILE(1, 63 * 128, 2);

    // ---- epilogue: C/D layout col = lane&15, row = (lane>>4)*4 + reg ----
    const int row0 = tm * 256 + wr * 128 + (lane >> 4) * 4;
    const int col0 = tn * 256 + wc * 64 + (lane & 15);
#pragma unroll
    for (int mi = 0; mi < 8; ++mi) {
#pragma unroll
        for (int ni = 0; ni < 4; ++ni) {
            const f32x4 v = acc[mi][ni];
            const size_t r = (size_t)(row0 + mi * 16);
            const int    c = col0 + ni * 16;
            C[(r + 0) * NDIM + c] = v[0];
            C[(r + 1) * NDIM + c] = v[1];
            C[(r + 2) * NDIM + c] = v[2];
            C[(r + 3) * NDIM + c] = v[3];
        }
    }
}

extern "C" void kernel_launch(void* const* d_in, const int* in_sizes, int n_in,
                              void* d_out, int out_size, void* d_ws, size_t ws_size,
                              hipStream_t stream) {
    const float* x      = (const float*)d_in[0];
    const float* R      = (const float*)d_in[1];
    const float* scales = (const float*)d_in[2];
    const float* zeros  = (const float*)d_in[3];
    const int*   perm   = (const int*)d_in[4];
    const int*   qw     = (const int*)d_in[5];
    float*       out    = (float*)d_out;

    unsigned short* xt = (unsigned short*)d_ws;          // 64 MiB
    unsigned short* wd = xt + (size_t)M_TOK * KDIM;      // 86 MiB

    rotate_kernel<<<dim3(KDIM / 256, M_TOK / 16), 256, 0, stream>>>(x, R, perm, xt);
    dequant_kernel<<<dim3((int)(((size_t)NDIM * KDIM) / 8 / 256)), 256, 0, stream>>>(qw, scales, zeros, wd);
    gemm_bt256<<<dim3((M_TOK / 256) * (NDIM / 256)), 512, 0, stream>>>(xt, wd, out);
}

// Round 10
// 748.530 us; speedup vs baseline: 1.6055x; 1.0055x over previous
//
#include <hip/hip_runtime.h>
#include <hip/hip_bf16.h>
#include <stdint.h>

#define M_TOK 8192
#define KDIM  4096
#define NDIM  11008
#define K2    8192     // KDIM * 2 bytes (row stride of xt/wd)

typedef __bf16 bf16x8 __attribute__((ext_vector_type(8)));
typedef float  f32x4  __attribute__((ext_vector_type(4)));
typedef unsigned short ushort8 __attribute__((ext_vector_type(8)));

__device__ __forceinline__ unsigned short f2b(float f) {
    union { float f; unsigned int i; } v; v.f = f;
    unsigned int u = v.i;
    unsigned int r = (u + 0x7fffu + ((u >> 16) & 1u)) >> 16;
    return (unsigned short)r;
}

__device__ __forceinline__ void gl_lds16(const void* g, void* l) {
    __builtin_amdgcn_global_load_lds(
        (const __attribute__((address_space(1))) unsigned int*)g,
        (__attribute__((address_space(3))) unsigned int*)l, 16, 0, 0);
}

// ---------------------------------------------------------------------------
// Rotate (write-coalesced, round-8 verified)
// ---------------------------------------------------------------------------
__global__ __launch_bounds__(256) void rotate_kernel(
    const float* __restrict__ x, const float* __restrict__ R,
    const int* __restrict__ perm, unsigned short* __restrict__ xt)
{
    __shared__ float Rs[16 * 273];
    __shared__ int   ps[256];
    const int bg = blockIdx.x;
    const int mc = blockIdx.y;
    const int t  = threadIdx.x;

    ps[t] = perm[bg * 256 + t];
    {
        const float* Rg = R + (size_t)bg * 4096;
#pragma unroll
        for (int k = 0; k < 16; ++k) {
            const int idx = t * 16 + k;
            const int bs = idx >> 8;
            const int i  = (idx >> 4) & 15;
            const int j  = idx & 15;
            Rs[bs * 273 + i * 17 + j] = Rg[idx];
        }
    }
    __syncthreads();

    const int bs = t & 15;
    const int r  = t >> 4;
    const int m  = mc * 16 + r;
    const float* xrow = x + (size_t)m * KDIM;

    float xv[16];
#pragma unroll
    for (int i = 0; i < 16; ++i) xv[i] = xrow[ps[bs * 16 + i]];

    float o[16];
#pragma unroll
    for (int j = 0; j < 16; ++j) o[j] = 0.f;
#pragma unroll
    for (int i = 0; i < 16; ++i) {
        const float xi = xv[i];
        const float* Rrow = &Rs[bs * 273 + i * 17];
#pragma unroll
        for (int j = 0; j < 16; ++j) o[j] += xi * Rrow[j];
    }

    unsigned short os[16] __attribute__((aligned(16)));
#pragma unroll
    for (int j = 0; j < 16; ++j) os[j] = f2b(o[j]);
    unsigned short* dst = xt + (size_t)m * KDIM + bg * 256 + bs * 16;
    *(ushort8*)dst       = *(ushort8*)os;
    *(ushort8*)(dst + 8) = *(ushort8*)(os + 8);
}

// ---------------------------------------------------------------------------
// Dequant
// ---------------------------------------------------------------------------
__global__ __launch_bounds__(256) void dequant_kernel(
    const int* __restrict__ q, const float* __restrict__ scales,
    const float* __restrict__ zeros, unsigned short* __restrict__ w)
{
    const int idx8 = blockIdx.x * 256 + threadIdx.x;
    const size_t base = (size_t)idx8 * 8;
    const int n = (int)(base >> 12);
    const float s = scales[n];
    const float z = zeros[n];
    const int4* qp = (const int4*)(q + base);
    const int4 q0 = qp[0], q1 = qp[1];
    unsigned short o[8] __attribute__((aligned(16)));
    o[0] = f2b(((float)q0.x - z) * s);
    o[1] = f2b(((float)q0.y - z) * s);
    o[2] = f2b(((float)q0.z - z) * s);
    o[3] = f2b(((float)q0.w - z) * s);
    o[4] = f2b(((float)q1.x - z) * s);
    o[5] = f2b(((float)q1.y - z) * s);
    o[6] = f2b(((float)q1.z - z) * s);
    o[7] = f2b(((float)q1.w - z) * s);
    *(ushort8*)(w + base) = *(ushort8*)o;
}

// ---------------------------------------------------------------------------
// Shared schedule macros (round-4 verified)
// ---------------------------------------------------------------------------
#define BAR() do { asm volatile("" ::: "memory"); __builtin_amdgcn_s_barrier(); \
                   asm volatile("" ::: "memory"); } while (0)
#define WAITV(n) asm volatile("s_waitcnt vmcnt(" #n ")" ::: "memory")
#define PRIO1 __builtin_amdgcn_s_setprio(1)
#define PRIO0 __builtin_amdgcn_s_setprio(0)

// ======================= MAIN: 256x256, tiles tn 0..39 =====================
#define ABASE(bb) ((bb)*65536)
#define BBASE(bb) ((bb)*65536 + 32768)

#define STAGE_A(bb, kB) do { \
    gl_lds16(aStageBase + (size_t)(  0)*K2 + (kB), lds + ABASE(bb) +     0 + wOff); \
    gl_lds16(aStageBase + (size_t)( 64)*K2 + (kB), lds + ABASE(bb) +  8192 + wOff); \
    gl_lds16(aStageBase + (size_t)(128)*K2 + (kB), lds + ABASE(bb) + 16384 + wOff); \
    gl_lds16(aStageBase + (size_t)(192)*K2 + (kB), lds + ABASE(bb) + 24576 + wOff); \
} while (0)
#define STAGE_B0(bb, kB) do { \
    gl_lds16(bStageBase + (size_t)(  0)*K2 + (kB), lds + BBASE(bb) +     0 + wOff); \
    gl_lds16(bStageBase + (size_t)( 64)*K2 + (kB), lds + BBASE(bb) +  8192 + wOff); \
} while (0)
#define STAGE_B1(bb, kB) do { \
    gl_lds16(bStageBase + (size_t)(128)*K2 + (kB), lds + BBASE(bb) + 16384 + wOff); \
    gl_lds16(bStageBase + (size_t)(192)*K2 + (kB), lds + BBASE(bb) + 24576 + wOff); \
} while (0)

#define PH_READ_A(bb, mh) do { \
    _Pragma("unroll") \
    for (int mf = 0; mf < 4; ++mf) { \
        aF[mf][0] = *(const bf16x8*)(lds + ABASE(bb) + aRdBase + ((mh)*64 + mf*16)*128 + cs0); \
        aF[mf][1] = *(const bf16x8*)(lds + ABASE(bb) + aRdBase + ((mh)*64 + mf*16)*128 + cs1); \
    } \
} while (0)
#define PH_READ_B(bb, nh) do { \
    _Pragma("unroll") \
    for (int nf = 0; nf < 2; ++nf) { \
        bF[nh][nf][0] = *(const bf16x8*)(lds + BBASE(bb) + bRdBase + ((nh)*32 + nf*16)*128 + cs0); \
        bF[nh][nf][1] = *(const bf16x8*)(lds + BBASE(bb) + bRdBase + ((nh)*32 + nf*16)*128 + cs1); \
    } \
} while (0)

#define MFMA_Q(mh, nh) do { \
    _Pragma("unroll") \
    for (int mf = 0; mf < 4; ++mf) \
    _Pragma("unroll") \
    for (int nf = 0; nf < 2; ++nf) { \
        acc[(mh)*4+mf][(nh)*2+nf] = __builtin_amdgcn_mfma_f32_16x16x32_bf16( \
            aF[mf][0], bF[nh][nf][0], acc[(mh)*4+mf][(nh)*2+nf], 0, 0, 0); \
        acc[(mh)*4+mf][(nh)*2+nf] = __builtin_amdgcn_mfma_f32_16x16x32_bf16( \
            aF[mf][1], bF[nh][nf][1], acc[(mh)*4+mf][(nh)*2+nf], 0, 0, 0); \
    } \
} while (0)

#define TILE(bb, kB, MODE) do { \
    PH_READ_A(bb, 0); PH_READ_B(bb, 0); \
    if ((MODE) <= 1) STAGE_B0((bb)^1, (kB) + 128); \
    BAR(); PRIO1; MFMA_Q(0, 0); PRIO0; BAR(); \
    PH_READ_B(bb, 1); \
    if ((MODE) <= 1) STAGE_B1((bb)^1, (kB) + 128); \
    BAR(); PRIO1; MFMA_Q(0, 1); PRIO0; BAR(); \
    PH_READ_A(bb, 1); \
    BAR(); PRIO1; MFMA_Q(1, 0); PRIO0; BAR(); \
    if ((MODE) == 0) STAGE_A(bb, (kB) + 256); \
    PRIO1; MFMA_Q(1, 1); PRIO0; \
    if ((MODE) == 0) WAITV(4); \
    if ((MODE) == 1) WAITV(0); \
    BAR(); \
} while (0)

__global__ __launch_bounds__(512, 2) void gemm_bt256(
    const unsigned short* __restrict__ Aq, const unsigned short* __restrict__ Bq,
    float* __restrict__ C)
{
    __shared__ char lds[131072];

    const int tid  = threadIdx.x;
    const int wave = tid >> 6;
    const int lane = tid & 63;
    const int wr   = wave >> 2;
    const int wc   = wave & 3;

    // 1280 tiles = 8 XCD chunks * 160; stripes of 4 tn, within-stripe tm*4+tn
    const int wg  = blockIdx.x;
    const int swz = (wg & 7) * 160 + (wg >> 3);
    const int S = swz >> 7;          // stripe 0..9
    const int L = swz & 127;
    const int tm = L >> 2;           // 0..31
    const int tn = (S << 2) + (L & 3);   // 0..39

    const int gRow    = wave * 8 + (lane >> 3);
    const int gColSwz = (((lane & 7) ^ ((lane >> 3) & 7)) << 4);
    const char* aStageBase = (const char*)Aq + (size_t)(tm * 256 + gRow) * K2 + gColSwz;
    const char* bStageBase = (const char*)Bq + (size_t)(tn * 256 + gRow) * K2 + gColSwz;
    const int wOff = wave * 1024;

    const int laneRow128 = (lane & 15) * 128;
    const int lx  = (lane & 7) << 4;
    const int cs0 = (((lane >> 4) * 16)      ) ^ lx;
    const int cs1 = (((lane >> 4) * 16) + 64 ) ^ lx;
    const int aRdBase = wr * 16384 + laneRow128;
    const int bRdBase = (wc >> 1) * 16384 + (wc & 1) * 8192 + laneRow128;

    f32x4  acc[8][4] = {};
    bf16x8 aF[4][2];
    bf16x8 bF[2][2][2];

    STAGE_A(0, 0);
    STAGE_B0(0, 0); STAGE_B1(0, 0);
    STAGE_A(1, 128);
    WAITV(4);
    BAR();

    int kB = 0;
#pragma unroll 1
    for (int t = 0; t < 61; t += 2) {
        TILE(0, kB, 0);
        TILE(1, kB + 128, 0);
        kB += 256;
    }
    TILE(0, 62 * 128, 1);
    TILE(1, 63 * 128, 2);

    const int row0 = tm * 256 + wr * 128 + (lane >> 4) * 4;
    const int col0 = tn * 256 + wc * 64 + (lane & 15);
#pragma unroll
    for (int mi = 0; mi < 8; ++mi) {
#pragma unroll
        for (int ni = 0; ni < 4; ++ni) {
            const f32x4 v = acc[mi][ni];
            const size_t r = (size_t)(row0 + mi * 16);
            const int    c = col0 + ni * 16;
            C[(r + 0) * NDIM + c] = v[0];
            C[(r + 1) * NDIM + c] = v[1];
            C[(r + 2) * NDIM + c] = v[2];
            C[(r + 3) * NDIM + c] = v[3];
        }
    }
}

// ================= TAIL: 128x256 half-tiles, tn 40..42 (192 blocks) ========
#define TAB(bb) ((bb)*16384)
#define TBB(bb) (32768 + (bb)*32768)

#define STAGE_TA(bb, kB) do { \
    gl_lds16(aStageBase + (size_t)(  0)*K2 + (kB), lds + TAB(bb) +    0 + wOff); \
    gl_lds16(aStageBase + (size_t)( 64)*K2 + (kB), lds + TAB(bb) + 8192 + wOff); \
} while (0)
#define STAGE_TB0(bb, kB) do { \
    gl_lds16(bStageBase + (size_t)(  0)*K2 + (kB), lds + TBB(bb) +     0 + wOff); \
    gl_lds16(bStageBase + (size_t)( 64)*K2 + (kB), lds + TBB(bb) +  8192 + wOff); \
} while (0)
#define STAGE_TB1(bb, kB) do { \
    gl_lds16(bStageBase + (size_t)(128)*K2 + (kB), lds + TBB(bb) + 16384 + wOff); \
    gl_lds16(bStageBase + (size_t)(192)*K2 + (kB), lds + TBB(bb) + 24576 + wOff); \
} while (0)

#define PH_READ_TA(bb) do { \
    _Pragma("unroll") \
    for (int mf = 0; mf < 4; ++mf) { \
        aF[mf][0] = *(const bf16x8*)(lds + TAB(bb) + aRdBase + (mf*16)*128 + cs0); \
        aF[mf][1] = *(const bf16x8*)(lds + TAB(bb) + aRdBase + (mf*16)*128 + cs1); \
    } \
} while (0)
#define PH_READ_TB(bb, nh) do { \
    _Pragma("unroll") \
    for (int nf = 0; nf < 2; ++nf) { \
        bF[nh][nf][0] = *(const bf16x8*)(lds + TBB(bb) + bRdBase + ((nh)*32 + nf*16)*128 + cs0); \
        bF[nh][nf][1] = *(const bf16x8*)(lds + TBB(bb) + bRdBase + ((nh)*32 + nf*16)*128 + cs1); \
    } \
} while (0)

#define MFMA_TQ(nh) do { \
    _Pragma("unroll") \
    for (int mf = 0; mf < 4; ++mf) \
    _Pragma("unroll") \
    for (int nf = 0; nf < 2; ++nf) { \
        acc[mf][(nh)*2+nf] = __builtin_amdgcn_mfma_f32_16x16x32_bf16( \
            aF[mf][0], bF[nh][nf][0], acc[mf][(nh)*2+nf], 0, 0, 0); \
        acc[mf][(nh)*2+nf] = __builtin_amdgcn_mfma_f32_16x16x32_bf16( \
            aF[mf][1], bF[nh][nf][1], acc[mf][(nh)*2+nf], 0, 0, 0); \
    } \
} while (0)

#define TTILE(bb, kB, MODE) do { \
    PH_READ_TA(bb); PH_READ_TB(bb, 0); \
    if ((MODE) <= 1) STAGE_TB0((bb)^1, (kB) + 128); \
    BAR(); PRIO1; MFMA_TQ(0); PRIO0; BAR(); \
    PH_READ_TB(bb, 1); \
    if ((MODE) <= 1) STAGE_TB1((bb)^1, (kB) + 128); \
    BAR(); PRIO1; MFMA_TQ(1); PRIO0; \
    if ((MODE) == 0) STAGE_TA(bb, (kB) + 256); \
    if ((MODE) == 0) WAITV(2); \
    if ((MODE) == 1) WAITV(0); \
    BAR(); \
} while (0)

__global__ __launch_bounds__(512, 1) void gemm_tail(
    const unsigned short* __restrict__ Aq, const unsigned short* __restrict__ Bq,
    float* __restrict__ C)
{
    __shared__ char lds[98304];

    const int tid  = threadIdx.x;
    const int wave = tid >> 6;
    const int lane = tid & 63;
    const int wr   = wave >> 2;      // 0..1 (M halves of 64)
    const int wc   = wave & 3;       // 0..3 (N)

    const int h   = blockIdx.x;      // 0..191
    const int tn  = 40 + (h % 3);    // 40..42
    const int tmh = h / 3;           // 0..63 (128-row tiles)

    const int gRow    = wave * 8 + (lane >> 3);
    const int gColSwz = (((lane & 7) ^ ((lane >> 3) & 7)) << 4);
    const char* aStageBase = (const char*)Aq + (size_t)(tmh * 128 + gRow) * K2 + gColSwz;
    const char* bStageBase = (const char*)Bq + (size_t)(tn * 256 + gRow) * K2 + gColSwz;
    const int wOff = wave * 1024;

    const int laneRow128 = (lane & 15) * 128;
    const int lx  = (lane & 7) << 4;
    const int cs0 = (((lane >> 4) * 16)      ) ^ lx;
    const int cs1 = (((lane >> 4) * 16) + 64 ) ^ lx;
    const int aRdBase = wr * 8192 + laneRow128;       // wave's 64 rows of 128
    const int bRdBase = (wc >> 1) * 16384 + (wc & 1) * 8192 + laneRow128;

    f32x4  acc[4][4] = {};
    bf16x8 aF[4][2];
    bf16x8 bF[2][2][2];

    STAGE_TA(0, 0);
    STAGE_TB0(0, 0); STAGE_TB1(0, 0);
    STAGE_TA(1, 128);
    WAITV(2);
    BAR();

    int kB = 0;
#pragma unroll 1
    for (int t = 0; t < 61; t += 2) {
        TTILE(0, kB, 0);
        TTILE(1, kB + 128, 0);
        kB += 256;
    }
    TTILE(0, 62 * 128, 1);
    TTILE(1, 63 * 128, 2);

    const int row0 = tmh * 128 + wr * 64 + (lane >> 4) * 4;
    const int col0 = tn * 256 + wc * 64 + (lane & 15);
#pragma unroll
    for (int mi = 0; mi < 4; ++mi) {
#pragma unroll
        for (int ni = 0; ni < 4; ++ni) {
            const f32x4 v = acc[mi][ni];
            const size_t r = (size_t)(row0 + mi * 16);
            const int    c = col0 + ni * 16;
            C[(r + 0) * NDIM + c] = v[0];
            C[(r + 1) * NDIM + c] = v[1];
            C[(r + 2) * NDIM + c] = v[2];
            C[(r + 3) * NDIM + c] = v[3];
        }
    }
}

extern "C" void kernel_launch(void* const* d_in, const int* in_sizes, int n_in,
                              void* d_out, int out_size, void* d_ws, size_t ws_size,
                              hipStream_t stream) {
    const float* x      = (const float*)d_in[0];
    const float* R      = (const float*)d_in[1];
    const float* scales = (const float*)d_in[2];
    const float* zeros  = (const float*)d_in[3];
    const int*   perm   = (const int*)d_in[4];
    const int*   qw     = (const int*)d_in[5];
    float*       out    = (float*)d_out;

    unsigned short* xt = (unsigned short*)d_ws;          // 64 MiB
    unsigned short* wd = xt + (size_t)M_TOK * KDIM;      // 86 MiB

    rotate_kernel<<<dim3(KDIM / 256, M_TOK / 16), 256, 0, stream>>>(x, R, perm, xt);
    dequant_kernel<<<dim3((int)(((size_t)NDIM * KDIM) / 8 / 256)), 256, 0, stream>>>(qw, scales, zeros, wd);
    gemm_bt256<<<dim3(1280), 512, 0, stream>>>(xt, wd, out);
    gemm_tail<<<dim3(192), 512, 0, stream>>>(xt, wd, out);
}

// Round 11
// 714.483 us; speedup vs baseline: 1.6820x; 1.0477x over previous
//
#include <hip/hip_runtime.h>
#include <hip/hip_bf16.h>
#include <stdint.h>

#define M_TOK 8192
#define KDIM  4096
#define NDIM  11008
#define K2    8192     // KDIM * 2 bytes (row stride of xt/wd)

typedef __bf16 bf16x8 __attribute__((ext_vector_type(8)));
typedef float  f32x4  __attribute__((ext_vector_type(4)));
typedef unsigned short ushort8 __attribute__((ext_vector_type(8)));

__device__ __forceinline__ unsigned short f2b(float f) {
    union { float f; unsigned int i; } v; v.f = f;
    unsigned int u = v.i;
    unsigned int r = (u + 0x7fffu + ((u >> 16) & 1u)) >> 16;
    return (unsigned short)r;
}

__device__ __forceinline__ void gl_lds16(const void* g, void* l) {
    __builtin_amdgcn_global_load_lds(
        (const __attribute__((address_space(1))) unsigned int*)g,
        (__attribute__((address_space(3))) unsigned int*)l, 16, 0, 0);
}

// ---------------------------------------------------------------------------
// Rotate (write-coalesced, round-8 verified)
// ---------------------------------------------------------------------------
__global__ __launch_bounds__(256) void rotate_kernel(
    const float* __restrict__ x, const float* __restrict__ R,
    const int* __restrict__ perm, unsigned short* __restrict__ xt)
{
    __shared__ float Rs[16 * 273];
    __shared__ int   ps[256];
    const int bg = blockIdx.x;
    const int mc = blockIdx.y;
    const int t  = threadIdx.x;

    ps[t] = perm[bg * 256 + t];
    {
        const float* Rg = R + (size_t)bg * 4096;
#pragma unroll
        for (int k = 0; k < 16; ++k) {
            const int idx = t * 16 + k;
            const int bs = idx >> 8;
            const int i  = (idx >> 4) & 15;
            const int j  = idx & 15;
            Rs[bs * 273 + i * 17 + j] = Rg[idx];
        }
    }
    __syncthreads();

    const int bs = t & 15;
    const int r  = t >> 4;
    const int m  = mc * 16 + r;
    const float* xrow = x + (size_t)m * KDIM;

    float xv[16];
#pragma unroll
    for (int i = 0; i < 16; ++i) xv[i] = xrow[ps[bs * 16 + i]];

    float o[16];
#pragma unroll
    for (int j = 0; j < 16; ++j) o[j] = 0.f;
#pragma unroll
    for (int i = 0; i < 16; ++i) {
        const float xi = xv[i];
        const float* Rrow = &Rs[bs * 273 + i * 17];
#pragma unroll
        for (int j = 0; j < 16; ++j) o[j] += xi * Rrow[j];
    }

    unsigned short os[16] __attribute__((aligned(16)));
#pragma unroll
    for (int j = 0; j < 16; ++j) os[j] = f2b(o[j]);
    unsigned short* dst = xt + (size_t)m * KDIM + bg * 256 + bs * 16;
    *(ushort8*)dst       = *(ushort8*)os;
    *(ushort8*)(dst + 8) = *(ushort8*)(os + 8);
}

// ---------------------------------------------------------------------------
// Dequant
// ---------------------------------------------------------------------------
__global__ __launch_bounds__(256) void dequant_kernel(
    const int* __restrict__ q, const float* __restrict__ scales,
    const float* __restrict__ zeros, unsigned short* __restrict__ w)
{
    const int idx8 = blockIdx.x * 256 + threadIdx.x;
    const size_t base = (size_t)idx8 * 8;
    const int n = (int)(base >> 12);
    const float s = scales[n];
    const float z = zeros[n];
    const int4* qp = (const int4*)(q + base);
    const int4 q0 = qp[0], q1 = qp[1];
    unsigned short o[8] __attribute__((aligned(16)));
    o[0] = f2b(((float)q0.x - z) * s);
    o[1] = f2b(((float)q0.y - z) * s);
    o[2] = f2b(((float)q0.z - z) * s);
    o[3] = f2b(((float)q0.w - z) * s);
    o[4] = f2b(((float)q1.x - z) * s);
    o[5] = f2b(((float)q1.y - z) * s);
    o[6] = f2b(((float)q1.z - z) * s);
    o[7] = f2b(((float)q1.w - z) * s);
    *(ushort8*)(w + base) = *(ushort8*)o;
}

// ---------------------------------------------------------------------------
// Shared schedule primitives
// ---------------------------------------------------------------------------
#define BAR() do { asm volatile("" ::: "memory"); __builtin_amdgcn_s_barrier(); \
                   asm volatile("" ::: "memory"); } while (0)
#define WAITV(n) asm volatile("s_waitcnt vmcnt(" #n ")" ::: "memory")
#define PRIO1 __builtin_amdgcn_s_setprio(1)
#define PRIO0 __builtin_amdgcn_s_setprio(0)

// ======================= MAIN path: 256x256 tiles ==========================
#define ABASE(bb) ((bb)*65536)
#define BBASE(bb) ((bb)*65536 + 32768)

#define STAGE_A(bb, kB) do { \
    gl_lds16(aStageBase + (size_t)(  0)*K2 + (kB), lds + ABASE(bb) +     0 + wOff); \
    gl_lds16(aStageBase + (size_t)( 64)*K2 + (kB), lds + ABASE(bb) +  8192 + wOff); \
    gl_lds16(aStageBase + (size_t)(128)*K2 + (kB), lds + ABASE(bb) + 16384 + wOff); \
    gl_lds16(aStageBase + (size_t)(192)*K2 + (kB), lds + ABASE(bb) + 24576 + wOff); \
} while (0)
#define STAGE_B0(bb, kB) do { \
    gl_lds16(bStageBase + (size_t)(  0)*K2 + (kB), lds + BBASE(bb) +     0 + wOff); \
    gl_lds16(bStageBase + (size_t)( 64)*K2 + (kB), lds + BBASE(bb) +  8192 + wOff); \
} while (0)
#define STAGE_B1(bb, kB) do { \
    gl_lds16(bStageBase + (size_t)(128)*K2 + (kB), lds + BBASE(bb) + 16384 + wOff); \
    gl_lds16(bStageBase + (size_t)(192)*K2 + (kB), lds + BBASE(bb) + 24576 + wOff); \
} while (0)

// reads into an explicit register set (for cross-phase prefetch)
#define PH_READ_A2(bb, mh, dst) do { \
    _Pragma("unroll") \
    for (int mf = 0; mf < 4; ++mf) { \
        dst[mf][0] = *(const bf16x8*)(lds + ABASE(bb) + aRdBase + ((mh)*64 + mf*16)*128 + cs0); \
        dst[mf][1] = *(const bf16x8*)(lds + ABASE(bb) + aRdBase + ((mh)*64 + mf*16)*128 + cs1); \
    } \
} while (0)
#define PH_READ_B2(bb, nh, dst) do { \
    _Pragma("unroll") \
    for (int nf = 0; nf < 2; ++nf) { \
        dst[nf][0] = *(const bf16x8*)(lds + BBASE(bb) + bRdBase + ((nh)*32 + nf*16)*128 + cs0); \
        dst[nf][1] = *(const bf16x8*)(lds + BBASE(bb) + bRdBase + ((nh)*32 + nf*16)*128 + cs1); \
    } \
} while (0)

#define MFMA_QX(mh, nh, Aset, Bset) do { \
    _Pragma("unroll") \
    for (int mf = 0; mf < 4; ++mf) \
    _Pragma("unroll") \
    for (int nf = 0; nf < 2; ++nf) { \
        acc[(mh)*4+mf][(nh)*2+nf] = __builtin_amdgcn_mfma_f32_16x16x32_bf16( \
            Aset[mf][0], Bset[nf][0], acc[(mh)*4+mf][(nh)*2+nf], 0, 0, 0); \
        acc[(mh)*4+mf][(nh)*2+nf] = __builtin_amdgcn_mfma_f32_16x16x32_bf16( \
            Aset[mf][1], Bset[nf][1], acc[(mh)*4+mf][(nh)*2+nf], 0, 0, 0); \
    } \
} while (0)

// Pipelined K-tile: quadrant q+1's ds_reads issue BEFORE quadrant q's MFMA
// cluster (reg double-buffer), so LDS-read latency/throughput hides under
// MFMA. Barriers: mid (A-overwrite guard) + boundary only. Staging order and
// counted WAITV(4) identical to the round-4..10 verified scheme.
#define TILE(bb, kB, MODE) do { \
    PH_READ_A2(bb, 0, aF0); PH_READ_B2(bb, 0, bG0); \
    if ((MODE) <= 1) STAGE_B0((bb)^1, (kB) + 128); \
    PH_READ_B2(bb, 1, bG1); \
    PRIO1; MFMA_QX(0, 0, aF0, bG0); PRIO0; \
    if ((MODE) <= 1) STAGE_B1((bb)^1, (kB) + 128); \
    PH_READ_A2(bb, 1, aF1); \
    PRIO1; MFMA_QX(0, 1, aF0, bG1); PRIO0; \
    BAR(); \
    if ((MODE) == 0) STAGE_A(bb, (kB) + 256); \
    PRIO1; MFMA_QX(1, 0, aF1, bG0); PRIO0; \
    PRIO1; MFMA_QX(1, 1, aF1, bG1); PRIO0; \
    if ((MODE) == 0) WAITV(4); \
    if ((MODE) == 1) WAITV(0); \
    BAR(); \
} while (0)

// ======================= TAIL path: 128x256 half-tiles =====================
#define TAB(bb) ((bb)*16384)
#define TBB(bb) (32768 + (bb)*32768)

#define STAGE_TA(bb, kB) do { \
    gl_lds16(aStageBase + (size_t)(  0)*K2 + (kB), lds + TAB(bb) +    0 + wOff); \
    gl_lds16(aStageBase + (size_t)( 64)*K2 + (kB), lds + TAB(bb) + 8192 + wOff); \
} while (0)
#define STAGE_TB0(bb, kB) do { \
    gl_lds16(bStageBase + (size_t)(  0)*K2 + (kB), lds + TBB(bb) +     0 + wOff); \
    gl_lds16(bStageBase + (size_t)( 64)*K2 + (kB), lds + TBB(bb) +  8192 + wOff); \
} while (0)
#define STAGE_TB1(bb, kB) do { \
    gl_lds16(bStageBase + (size_t)(128)*K2 + (kB), lds + TBB(bb) + 16384 + wOff); \
    gl_lds16(bStageBase + (size_t)(192)*K2 + (kB), lds + TBB(bb) + 24576 + wOff); \
} while (0)

#define PH_READ_TA(bb) do { \
    _Pragma("unroll") \
    for (int mf = 0; mf < 4; ++mf) { \
        aF[mf][0] = *(const bf16x8*)(lds + TAB(bb) + aRdBase + (mf*16)*128 + cs0); \
        aF[mf][1] = *(const bf16x8*)(lds + TAB(bb) + aRdBase + (mf*16)*128 + cs1); \
    } \
} while (0)
#define PH_READ_TB(bb, nh) do { \
    _Pragma("unroll") \
    for (int nf = 0; nf < 2; ++nf) { \
        bF[nh][nf][0] = *(const bf16x8*)(lds + TBB(bb) + bRdBase + ((nh)*32 + nf*16)*128 + cs0); \
        bF[nh][nf][1] = *(const bf16x8*)(lds + TBB(bb) + bRdBase + ((nh)*32 + nf*16)*128 + cs1); \
    } \
} while (0)

#define MFMA_TQ(nh) do { \
    _Pragma("unroll") \
    for (int mf = 0; mf < 4; ++mf) \
    _Pragma("unroll") \
    for (int nf = 0; nf < 2; ++nf) { \
        acc[mf][(nh)*2+nf] = __builtin_amdgcn_mfma_f32_16x16x32_bf16( \
            aF[mf][0], bF[nh][nf][0], acc[mf][(nh)*2+nf], 0, 0, 0); \
        acc[mf][(nh)*2+nf] = __builtin_amdgcn_mfma_f32_16x16x32_bf16( \
            aF[mf][1], bF[nh][nf][1], acc[mf][(nh)*2+nf], 0, 0, 0); \
    } \
} while (0)

#define TTILE(bb, kB, MODE) do { \
    PH_READ_TA(bb); PH_READ_TB(bb, 0); \
    if ((MODE) <= 1) STAGE_TB0((bb)^1, (kB) + 128); \
    BAR(); PRIO1; MFMA_TQ(0); PRIO0; BAR(); \
    PH_READ_TB(bb, 1); \
    if ((MODE) <= 1) STAGE_TB1((bb)^1, (kB) + 128); \
    BAR(); PRIO1; MFMA_TQ(1); PRIO0; \
    if ((MODE) == 0) STAGE_TA(bb, (kB) + 256); \
    if ((MODE) == 0) WAITV(2); \
    if ((MODE) == 1) WAITV(0); \
    BAR(); \
} while (0)

// ---------------------------------------------------------------------------
// Merged GEMM: blocks 0..1279 = 256x256 main tiles (tn 0..39, 5 rounds);
// blocks 1280..1471 = 128x256 tail half-tiles (tn 40..42) that fill CUs as
// round-5 stragglers finish (1280 % 8 == 0 keeps XCD chunking valid).
// ---------------------------------------------------------------------------
__global__ __launch_bounds__(512, 2) void gemm_all(
    const unsigned short* __restrict__ Aq, const unsigned short* __restrict__ Bq,
    float* __restrict__ C)
{
    __shared__ char lds[131072];

    const int tid  = threadIdx.x;
    const int wave = tid >> 6;
    const int lane = tid & 63;
    const int wr   = wave >> 2;
    const int wc   = wave & 3;
    const int wg   = blockIdx.x;

    const int gRow    = wave * 8 + (lane >> 3);
    const int gColSwz = (((lane & 7) ^ ((lane >> 3) & 7)) << 4);
    const int wOff    = wave * 1024;

    const int laneRow128 = (lane & 15) * 128;
    const int lx  = (lane & 7) << 4;
    const int cs0 = (((lane >> 4) * 16)      ) ^ lx;
    const int cs1 = (((lane >> 4) * 16) + 64 ) ^ lx;

    if (wg < 1280) {
        // ================= MAIN =================
        const int swz = (wg & 7) * 160 + (wg >> 3);
        const int S = swz >> 7;
        const int L = swz & 127;
        const int tm = L >> 2;
        const int tn = (S << 2) + (L & 3);

        const char* aStageBase = (const char*)Aq + (size_t)(tm * 256 + gRow) * K2 + gColSwz;
        const char* bStageBase = (const char*)Bq + (size_t)(tn * 256 + gRow) * K2 + gColSwz;

        const int aRdBase = wr * 16384 + laneRow128;
        const int bRdBase = (wc >> 1) * 16384 + (wc & 1) * 8192 + laneRow128;

        f32x4  acc[8][4] = {};
        bf16x8 aF0[4][2], aF1[4][2];
        bf16x8 bG0[2][2], bG1[2][2];

        STAGE_A(0, 0);
        STAGE_B0(0, 0); STAGE_B1(0, 0);
        STAGE_A(1, 128);
        WAITV(4);
        BAR();

        int kB = 0;
#pragma unroll 1
        for (int t = 0; t < 61; t += 2) {
            TILE(0, kB, 0);
            TILE(1, kB + 128, 0);
            kB += 256;
        }
        TILE(0, 62 * 128, 1);
        TILE(1, 63 * 128, 2);

        const int row0 = tm * 256 + wr * 128 + (lane >> 4) * 4;
        const int col0 = tn * 256 + wc * 64 + (lane & 15);
#pragma unroll
        for (int mi = 0; mi < 8; ++mi) {
#pragma unroll
            for (int ni = 0; ni < 4; ++ni) {
                const f32x4 v = acc[mi][ni];
                const size_t r = (size_t)(row0 + mi * 16);
                const int    c = col0 + ni * 16;
                C[(r + 0) * NDIM + c] = v[0];
                C[(r + 1) * NDIM + c] = v[1];
                C[(r + 2) * NDIM + c] = v[2];
                C[(r + 3) * NDIM + c] = v[3];
            }
        }
    } else {
        // ================= TAIL =================
        const int h   = wg - 1280;       // 0..191
        const int tn  = 40 + (h % 3);
        const int tmh = h / 3;

        const char* aStageBase = (const char*)Aq + (size_t)(tmh * 128 + gRow) * K2 + gColSwz;
        const char* bStageBase = (const char*)Bq + (size_t)(tn * 256 + gRow) * K2 + gColSwz;

        const int aRdBase = wr * 8192 + laneRow128;
        const int bRdBase = (wc >> 1) * 16384 + (wc & 1) * 8192 + laneRow128;

        f32x4  acc[4][4] = {};
        bf16x8 aF[4][2];
        bf16x8 bF[2][2][2];

        STAGE_TA(0, 0);
        STAGE_TB0(0, 0); STAGE_TB1(0, 0);
        STAGE_TA(1, 128);
        WAITV(2);
        BAR();

        int kB = 0;
#pragma unroll 1
        for (int t = 0; t < 61; t += 2) {
            TTILE(0, kB, 0);
            TTILE(1, kB + 128, 0);
            kB += 256;
        }
        TTILE(0, 62 * 128, 1);
        TTILE(1, 63 * 128, 2);

        const int row0 = tmh * 128 + wr * 64 + (lane >> 4) * 4;
        const int col0 = tn * 256 + wc * 64 + (lane & 15);
#pragma unroll
        for (int mi = 0; mi < 4; ++mi) {
#pragma unroll
            for (int ni = 0; ni < 4; ++ni) {
                const f32x4 v = acc[mi][ni];
                const size_t r = (size_t)(row0 + mi * 16);
                const int    c = col0 + ni * 16;
                C[(r + 0) * NDIM + c] = v[0];
                C[(r + 1) * NDIM + c] = v[1];
                C[(r + 2) * NDIM + c] = v[2];
                C[(r + 3) * NDIM + c] = v[3];
            }
        }
    }
}

extern "C" void kernel_launch(void* const* d_in, const int* in_sizes, int n_in,
                              void* d_out, int out_size, void* d_ws, size_t ws_size,
                              hipStream_t stream) {
    const float* x      = (const float*)d_in[0];
    const float* R      = (const float*)d_in[1];
    const float* scales = (const float*)d_in[2];
    const float* zeros  = (const float*)d_in[3];
    const int*   perm   = (const int*)d_in[4];
    const int*   qw     = (const int*)d_in[5];
    float*       out    = (float*)d_out;

    unsigned short* xt = (unsigned short*)d_ws;          // 64 MiB
    unsigned short* wd = xt + (size_t)M_TOK * KDIM;      // 86 MiB

    rotate_kernel<<<dim3(KDIM / 256, M_TOK / 16), 256, 0, stream>>>(x, R, perm, xt);
    dequant_kernel<<<dim3((int)(((size_t)NDIM * KDIM) / 8 / 256)), 256, 0, stream>>>(qw, scales, zeros, wd);
    gemm_all<<<dim3(1472), 512, 0, stream>>>(xt, wd, out);
}

// Round 12
// 462.366 us; speedup vs baseline: 2.5992x; 1.5453x over previous
//
#include <hip/hip_runtime.h>
#include <hip/hip_bf16.h>
#include <stdint.h>

#define M_TOK 8192
#define KDIM  4096
#define NDIM  11008

typedef float  f32x4  __attribute__((ext_vector_type(4)));
typedef int    i32x4  __attribute__((ext_vector_type(4)));
typedef unsigned short ushort8 __attribute__((ext_vector_type(8)));

__device__ __forceinline__ unsigned short f2b(float f) {
    union { float f; unsigned int i; } v; v.f = f;
    unsigned int u = v.i;
    unsigned int r = (u + 0x7fffu + ((u >> 16) & 1u)) >> 16;
    return (unsigned short)r;
}
__device__ __forceinline__ float b2f(unsigned short u) {
    union { unsigned int i; float f; } v; v.i = ((unsigned int)u) << 16; return v.f;
}

__device__ __forceinline__ void gl_lds16(const void* g, void* l) {
    __builtin_amdgcn_global_load_lds(
        (const __attribute__((address_space(1))) unsigned int*)g,
        (__attribute__((address_space(3))) unsigned int*)l, 16, 0, 0);
}

// ---------------------------------------------------------------------------
// Rotate (round-8 verified write-coalesced) + per-(row, 256-col-group) max.
// xt bf16 intermediate; pmax[m][bg] feeds the pack kernel's row scale.
// ---------------------------------------------------------------------------
__global__ __launch_bounds__(256) void rotate_kernel(
    const float* __restrict__ x, const float* __restrict__ R,
    const int* __restrict__ perm, unsigned short* __restrict__ xt,
    float* __restrict__ pmax)
{
    __shared__ float Rs[16 * 273];
    __shared__ int   ps[256];
    const int bg = blockIdx.x;
    const int mc = blockIdx.y;
    const int t  = threadIdx.x;

    ps[t] = perm[bg * 256 + t];
    {
        const float* Rg = R + (size_t)bg * 4096;
#pragma unroll
        for (int k = 0; k < 16; ++k) {
            const int idx = t * 16 + k;
            const int bs = idx >> 8;
            const int i  = (idx >> 4) & 15;
            const int j  = idx & 15;
            Rs[bs * 273 + i * 17 + j] = Rg[idx];
        }
    }
    __syncthreads();

    const int bs = t & 15;
    const int r  = t >> 4;
    const int m  = mc * 16 + r;
    const float* xrow = x + (size_t)m * KDIM;

    float xv[16];
#pragma unroll
    for (int i = 0; i < 16; ++i) xv[i] = xrow[ps[bs * 16 + i]];

    float o[16];
#pragma unroll
    for (int j = 0; j < 16; ++j) o[j] = 0.f;
#pragma unroll
    for (int i = 0; i < 16; ++i) {
        const float xi = xv[i];
        const float* Rrow = &Rs[bs * 273 + i * 17];
#pragma unroll
        for (int j = 0; j < 16; ++j) o[j] += xi * Rrow[j];
    }

    float lm = 0.f;
#pragma unroll
    for (int j = 0; j < 16; ++j) lm = fmaxf(lm, fabsf(o[j]));
#pragma unroll
    for (int k = 1; k < 16; k <<= 1) lm = fmaxf(lm, __shfl_xor(lm, k, 64));
    if (bs == 0) pmax[(size_t)m * 16 + bg] = lm;

    unsigned short os[16] __attribute__((aligned(16)));
#pragma unroll
    for (int j = 0; j < 16; ++j) os[j] = f2b(o[j]);
    unsigned short* dst = xt + (size_t)m * KDIM + bg * 256 + bs * 16;
    *(ushort8*)dst       = *(ushort8*)os;
    *(ushort8*)(dst + 8) = *(ushort8*)(os + 8);
}

// ---------------------------------------------------------------------------
// Pack: per-row amax -> s_a[m]; xt bf16 -> i8 (round, clamp); S[m] = sum(xtq).
// One block per row.
// ---------------------------------------------------------------------------
__global__ __launch_bounds__(256) void pack_kernel(
    const unsigned short* __restrict__ xt, const float* __restrict__ pmax,
    signed char* __restrict__ xt8, int* __restrict__ S, float* __restrict__ sa)
{
    const int m = blockIdx.x;
    const int t = threadIdx.x;

    float am = 1e-20f;
#pragma unroll
    for (int i = 0; i < 16; ++i) am = fmaxf(am, pmax[(size_t)m * 16 + i]);
    const float inv = 127.0f / am;

    const unsigned short* src = xt + (size_t)m * KDIM + t * 16;
    ushort8 u0 = *(const ushort8*)src;
    ushort8 u1 = *(const ushort8*)(src + 8);
    signed char qv[16] __attribute__((aligned(16)));
    int s = 0;
#pragma unroll
    for (int i = 0; i < 8; ++i) {
        int q0 = (int)rintf(b2f(u0[i]) * inv);
        q0 = q0 > 127 ? 127 : (q0 < -127 ? -127 : q0);
        qv[i] = (signed char)q0; s += q0;
        int q1 = (int)rintf(b2f(u1[i]) * inv);
        q1 = q1 > 127 ? 127 : (q1 < -127 ? -127 : q1);
        qv[8 + i] = (signed char)q1; s += q1;
    }
    *(int4*)(xt8 + (size_t)m * KDIM + t * 16) = *(const int4*)qv;

#pragma unroll
    for (int k = 1; k < 64; k <<= 1) s += __shfl_xor(s, k, 64);
    __shared__ int ws[4];
    if ((t & 63) == 0) ws[t >> 6] = s;
    __syncthreads();
    if (t == 0) {
        S[m]  = ws[0] + ws[1] + ws[2] + ws[3];
        sa[m] = am * (1.0f / 127.0f);
    }
}

// ---------------------------------------------------------------------------
// qpack: qweight int32 (0..15) -> i8 (exact)
// ---------------------------------------------------------------------------
__global__ __launch_bounds__(256) void qpack_kernel(
    const int* __restrict__ q, signed char* __restrict__ q8)
{
    const size_t base = ((size_t)blockIdx.x * 256 + threadIdx.x) * 16;
    const int4* qp = (const int4*)(q + base);
    signed char o[16] __attribute__((aligned(16)));
#pragma unroll
    for (int c = 0; c < 4; ++c) {
        const int4 v = qp[c];
        o[c*4+0] = (signed char)v.x; o[c*4+1] = (signed char)v.y;
        o[c*4+2] = (signed char)v.z; o[c*4+3] = (signed char)v.w;
    }
    *(int4*)(q8 + base) = *(const int4*)o;
}

// ---------------------------------------------------------------------------
// i8 GEMM: QK[m,n] = sum_k xtq[m,k]*q[n,k] (i32 exact), then
// C = sa[m]*sn[n]*(QK - z[n]*S[m]).  256x256 tiles, BK=128 (128 B/row i8),
// same verified schedule: (row&7)<<4 XOR swizzle (2-way = free), pre-swizzled
// global staging source + linear LDS dest, counted vmcnt(4), pipelined TILE
// (reg-dbuf frags, 2 barriers/K-tile), merged 128-row tail.
// mfma_i32_16x16x64_i8: A/B row|col = lane&15, k = (lane>>4)*16 + i (16 B);
// C/D col = lane&15, row = (lane>>4)*4 + reg (dtype-independent).
// ---------------------------------------------------------------------------
#define BAR() do { asm volatile("" ::: "memory"); __builtin_amdgcn_s_barrier(); \
                   asm volatile("" ::: "memory"); } while (0)
#define WAITV(n) asm volatile("s_waitcnt vmcnt(" #n ")" ::: "memory")
#define PRIO1 __builtin_amdgcn_s_setprio(1)
#define PRIO0 __builtin_amdgcn_s_setprio(0)

#define ABASE(bb) ((bb)*65536)
#define BBASE(bb) ((bb)*65536 + 32768)

#define STAGE_A(bb, kB) do { \
    gl_lds16(aStageBase + (size_t)(  0)*KDIM + (kB), lds + ABASE(bb) +     0 + wOff); \
    gl_lds16(aStageBase + (size_t)( 64)*KDIM + (kB), lds + ABASE(bb) +  8192 + wOff); \
    gl_lds16(aStageBase + (size_t)(128)*KDIM + (kB), lds + ABASE(bb) + 16384 + wOff); \
    gl_lds16(aStageBase + (size_t)(192)*KDIM + (kB), lds + ABASE(bb) + 24576 + wOff); \
} while (0)
#define STAGE_B0(bb, kB) do { \
    gl_lds16(bStageBase + (size_t)(  0)*KDIM + (kB), lds + BBASE(bb) +     0 + wOff); \
    gl_lds16(bStageBase + (size_t)( 64)*KDIM + (kB), lds + BBASE(bb) +  8192 + wOff); \
} while (0)
#define STAGE_B1(bb, kB) do { \
    gl_lds16(bStageBase + (size_t)(128)*KDIM + (kB), lds + BBASE(bb) + 16384 + wOff); \
    gl_lds16(bStageBase + (size_t)(192)*KDIM + (kB), lds + BBASE(bb) + 24576 + wOff); \
} while (0)

#define PH_READ_A2(bb, mh, dst) do { \
    _Pragma("unroll") \
    for (int mf = 0; mf < 4; ++mf) { \
        dst[mf][0] = *(const i32x4*)(lds + ABASE(bb) + aRdBase + ((mh)*64 + mf*16)*128 + cs0); \
        dst[mf][1] = *(const i32x4*)(lds + ABASE(bb) + aRdBase + ((mh)*64 + mf*16)*128 + cs1); \
    } \
} while (0)
#define PH_READ_B2(bb, nh, dst) do { \
    _Pragma("unroll") \
    for (int nf = 0; nf < 2; ++nf) { \
        dst[nf][0] = *(const i32x4*)(lds + BBASE(bb) + bRdBase + ((nh)*32 + nf*16)*128 + cs0); \
        dst[nf][1] = *(const i32x4*)(lds + BBASE(bb) + bRdBase + ((nh)*32 + nf*16)*128 + cs1); \
    } \
} while (0)

#define MFMA_QX(mh, nh, Aset, Bset) do { \
    _Pragma("unroll") \
    for (int mf = 0; mf < 4; ++mf) \
    _Pragma("unroll") \
    for (int nf = 0; nf < 2; ++nf) { \
        acc[(mh)*4+mf][(nh)*2+nf] = __builtin_amdgcn_mfma_i32_16x16x64_i8( \
            Aset[mf][0], Bset[nf][0], acc[(mh)*4+mf][(nh)*2+nf], 0, 0, 0); \
        acc[(mh)*4+mf][(nh)*2+nf] = __builtin_amdgcn_mfma_i32_16x16x64_i8( \
            Aset[mf][1], Bset[nf][1], acc[(mh)*4+mf][(nh)*2+nf], 0, 0, 0); \
    } \
} while (0)

#define TILE(bb, kB, MODE) do { \
    PH_READ_A2(bb, 0, aF0); PH_READ_B2(bb, 0, bG0); \
    if ((MODE) <= 1) STAGE_B0((bb)^1, (kB) + 128); \
    PH_READ_B2(bb, 1, bG1); \
    PRIO1; MFMA_QX(0, 0, aF0, bG0); PRIO0; \
    if ((MODE) <= 1) STAGE_B1((bb)^1, (kB) + 128); \
    PH_READ_A2(bb, 1, aF1); \
    PRIO1; MFMA_QX(0, 1, aF0, bG1); PRIO0; \
    BAR(); \
    if ((MODE) == 0) STAGE_A(bb, (kB) + 256); \
    PRIO1; MFMA_QX(1, 0, aF1, bG0); PRIO0; \
    PRIO1; MFMA_QX(1, 1, aF1, bG1); PRIO0; \
    if ((MODE) == 0) WAITV(4); \
    if ((MODE) == 1) WAITV(0); \
    BAR(); \
} while (0)

// tail (128x256) variants
#define TAB(bb) ((bb)*16384)
#define TBB(bb) (32768 + (bb)*32768)

#define STAGE_TA(bb, kB) do { \
    gl_lds16(aStageBase + (size_t)(  0)*KDIM + (kB), lds + TAB(bb) +    0 + wOff); \
    gl_lds16(aStageBase + (size_t)( 64)*KDIM + (kB), lds + TAB(bb) + 8192 + wOff); \
} while (0)
#define STAGE_TB0(bb, kB) do { \
    gl_lds16(bStageBase + (size_t)(  0)*KDIM + (kB), lds + TBB(bb) +     0 + wOff); \
    gl_lds16(bStageBase + (size_t)( 64)*KDIM + (kB), lds + TBB(bb) +  8192 + wOff); \
} while (0)
#define STAGE_TB1(bb, kB) do { \
    gl_lds16(bStageBase + (size_t)(128)*KDIM + (kB), lds + TBB(bb) + 16384 + wOff); \
    gl_lds16(bStageBase + (size_t)(192)*KDIM + (kB), lds + TBB(bb) + 24576 + wOff); \
} while (0)

#define PH_READ_TA(bb) do { \
    _Pragma("unroll") \
    for (int mf = 0; mf < 4; ++mf) { \
        aF[mf][0] = *(const i32x4*)(lds + TAB(bb) + aRdBase + (mf*16)*128 + cs0); \
        aF[mf][1] = *(const i32x4*)(lds + TAB(bb) + aRdBase + (mf*16)*128 + cs1); \
    } \
} while (0)
#define PH_READ_TB(bb, nh) do { \
    _Pragma("unroll") \
    for (int nf = 0; nf < 2; ++nf) { \
        bF[nh][nf][0] = *(const i32x4*)(lds + TBB(bb) + bRdBase + ((nh)*32 + nf*16)*128 + cs0); \
        bF[nh][nf][1] = *(const i32x4*)(lds + TBB(bb) + bRdBase + ((nh)*32 + nf*16)*128 + cs1); \
    } \
} while (0)

#define MFMA_TQ(nh) do { \
    _Pragma("unroll") \
    for (int mf = 0; mf < 4; ++mf) \
    _Pragma("unroll") \
    for (int nf = 0; nf < 2; ++nf) { \
        acc[mf][(nh)*2+nf] = __builtin_amdgcn_mfma_i32_16x16x64_i8( \
            aF[mf][0], bF[nh][nf][0], acc[mf][(nh)*2+nf], 0, 0, 0); \
        acc[mf][(nh)*2+nf] = __builtin_amdgcn_mfma_i32_16x16x64_i8( \
            aF[mf][1], bF[nh][nf][1], acc[mf][(nh)*2+nf], 0, 0, 0); \
    } \
} while (0)

#define TTILE(bb, kB, MODE) do { \
    PH_READ_TA(bb); PH_READ_TB(bb, 0); \
    if ((MODE) <= 1) STAGE_TB0((bb)^1, (kB) + 128); \
    BAR(); PRIO1; MFMA_TQ(0); PRIO0; BAR(); \
    PH_READ_TB(bb, 1); \
    if ((MODE) <= 1) STAGE_TB1((bb)^1, (kB) + 128); \
    BAR(); PRIO1; MFMA_TQ(1); PRIO0; \
    if ((MODE) == 0) STAGE_TA(bb, (kB) + 256); \
    if ((MODE) == 0) WAITV(2); \
    if ((MODE) == 1) WAITV(0); \
    BAR(); \
} while (0)

__global__ __launch_bounds__(512, 2) void gemm_all(
    const signed char* __restrict__ Aq, const signed char* __restrict__ Bq,
    const float* __restrict__ sn, const float* __restrict__ zz,
    const float* __restrict__ sa, const int* __restrict__ S,
    float* __restrict__ C)
{
    __shared__ char lds[131072];

    const int tid  = threadIdx.x;
    const int wave = tid >> 6;
    const int lane = tid & 63;
    const int wr   = wave >> 2;
    const int wc   = wave & 3;
    const int wg   = blockIdx.x;

    const int gRow    = wave * 8 + (lane >> 3);
    const int gColSwz = (((lane & 7) ^ ((lane >> 3) & 7)) << 4);
    const int wOff    = wave * 1024;

    const int laneRow128 = (lane & 15) * 128;
    const int lx  = (lane & 7) << 4;
    const int cs0 = (((lane >> 4) * 16)      ) ^ lx;   // k 0..63
    const int cs1 = (((lane >> 4) * 16) + 64 ) ^ lx;   // k 64..127

    if (wg < 1280) {
        // ================= MAIN: 256x256, tn 0..39 =================
        const int swz = (wg & 7) * 160 + (wg >> 3);
        const int Sx = swz >> 7;
        const int L  = swz & 127;
        const int tm = L >> 2;
        const int tn = (Sx << 2) + (L & 3);

        const char* aStageBase = (const char*)Aq + (size_t)(tm * 256 + gRow) * KDIM + gColSwz;
        const char* bStageBase = (const char*)Bq + (size_t)(tn * 256 + gRow) * KDIM + gColSwz;

        const int aRdBase = wr * 16384 + laneRow128;
        const int bRdBase = (wc >> 1) * 16384 + (wc & 1) * 8192 + laneRow128;

        i32x4 acc[8][4] = {};
        i32x4 aF0[4][2], aF1[4][2];
        i32x4 bG0[2][2], bG1[2][2];

        STAGE_A(0, 0);
        STAGE_B0(0, 0); STAGE_B1(0, 0);
        STAGE_A(1, 128);
        WAITV(4);
        BAR();

        int kB = 0;
#pragma unroll 1
        for (int t = 0; t < 29; t += 2) {       // 32 K-tiles of BK=128
            TILE(0, kB, 0);
            TILE(1, kB + 128, 0);
            kB += 256;
        }
        TILE(0, 30 * 128, 1);
        TILE(1, 31 * 128, 2);

        const int row0 = tm * 256 + wr * 128 + (lane >> 4) * 4;
        const int col0 = tn * 256 + wc * 64 + (lane & 15);
        float sn4[4], z4[4];
#pragma unroll
        for (int ni = 0; ni < 4; ++ni) { sn4[ni] = sn[col0 + ni*16]; z4[ni] = zz[col0 + ni*16]; }
#pragma unroll
        for (int mi = 0; mi < 8; ++mi) {
            const int rbase = row0 + mi * 16;
            float sa4[4], Sf4[4];
#pragma unroll
            for (int j = 0; j < 4; ++j) { sa4[j] = sa[rbase + j]; Sf4[j] = (float)S[rbase + j]; }
#pragma unroll
            for (int ni = 0; ni < 4; ++ni) {
                const i32x4 v = acc[mi][ni];
                const int c = col0 + ni * 16;
#pragma unroll
                for (int j = 0; j < 4; ++j)
                    C[(size_t)(rbase + j) * NDIM + c] = sa4[j] * sn4[ni] * ((float)v[j] - z4[ni] * Sf4[j]);
            }
        }
    } else {
        // ================= TAIL: 128x256, tn 40..42 =================
        const int h   = wg - 1280;
        const int tn  = 40 + (h % 3);
        const int tmh = h / 3;

        const char* aStageBase = (const char*)Aq + (size_t)(tmh * 128 + gRow) * KDIM + gColSwz;
        const char* bStageBase = (const char*)Bq + (size_t)(tn * 256 + gRow) * KDIM + gColSwz;

        const int aRdBase = wr * 8192 + laneRow128;
        const int bRdBase = (wc >> 1) * 16384 + (wc & 1) * 8192 + laneRow128;

        i32x4 acc[4][4] = {};
        i32x4 aF[4][2];
        i32x4 bF[2][2][2];

        STAGE_TA(0, 0);
        STAGE_TB0(0, 0); STAGE_TB1(0, 0);
        STAGE_TA(1, 128);
        WAITV(2);
        BAR();

        int kB = 0;
#pragma unroll 1
        for (int t = 0; t < 29; t += 2) {
            TTILE(0, kB, 0);
            TTILE(1, kB + 128, 0);
            kB += 256;
        }
        TTILE(0, 30 * 128, 1);
        TTILE(1, 31 * 128, 2);

        const int row0 = tmh * 128 + wr * 64 + (lane >> 4) * 4;
        const int col0 = tn * 256 + wc * 64 + (lane & 15);
        float sn4[4], z4[4];
#pragma unroll
        for (int ni = 0; ni < 4; ++ni) { sn4[ni] = sn[col0 + ni*16]; z4[ni] = zz[col0 + ni*16]; }
#pragma unroll
        for (int mi = 0; mi < 4; ++mi) {
            const int rbase = row0 + mi * 16;
            float sa4[4], Sf4[4];
#pragma unroll
            for (int j = 0; j < 4; ++j) { sa4[j] = sa[rbase + j]; Sf4[j] = (float)S[rbase + j]; }
#pragma unroll
            for (int ni = 0; ni < 4; ++ni) {
                const i32x4 v = acc[mi][ni];
                const int c = col0 + ni * 16;
#pragma unroll
                for (int j = 0; j < 4; ++j)
                    C[(size_t)(rbase + j) * NDIM + c] = sa4[j] * sn4[ni] * ((float)v[j] - z4[ni] * Sf4[j]);
            }
        }
    }
}

extern "C" void kernel_launch(void* const* d_in, const int* in_sizes, int n_in,
                              void* d_out, int out_size, void* d_ws, size_t ws_size,
                              hipStream_t stream) {
    const float* x      = (const float*)d_in[0];
    const float* R      = (const float*)d_in[1];
    const float* scales = (const float*)d_in[2];
    const float* zeros  = (const float*)d_in[3];
    const int*   perm   = (const int*)d_in[4];
    const int*   qw     = (const int*)d_in[5];
    float*       out    = (float*)d_out;

    // workspace layout (bytes)
    char* ws = (char*)d_ws;
    unsigned short* xt16 = (unsigned short*)ws;                   //  64 MiB @ 0
    signed char*    xt8  = (signed char*)(ws + 67108864);         //  32 MiB
    signed char*    q8   = (signed char*)(ws + 100663296);        //  43 MiB
    float*          pmax = (float*)(ws + 145752064);              // 512 KiB
    float*          sa   = (float*)(ws + 146276352);              //  32 KiB
    int*            S    = (int*)(ws + 146309120);                //  32 KiB

    rotate_kernel<<<dim3(KDIM / 256, M_TOK / 16), 256, 0, stream>>>(x, R, perm, xt16, pmax);
    qpack_kernel<<<dim3((int)(((size_t)NDIM * KDIM) / 16 / 256)), 256, 0, stream>>>(qw, q8);
    pack_kernel<<<dim3(M_TOK), 256, 0, stream>>>(xt16, pmax, xt8, S, sa);
    gemm_all<<<dim3(1472), 512, 0, stream>>>(xt8, q8, scales, zeros, sa, S, out);
}